// Round 3
// baseline (417.905 us; speedup 1.0000x reference)
//
#include <hip/hip_runtime.h>
#include <stdint.h>

typedef unsigned long long u64;
typedef uint32_t u32;

#define BB 256
#define VV 128000
#define NV4 (VV / 4)          // 32000 float4 per row
#define NBUCK 4096
#define CAP 2048
#define QSCALE 1.099511627776e12f   // 2^40 fixed-point scale for q
#define QINV   (1.0 / 1099511627776.0)

__device__ __forceinline__ u32 rotl32(u32 v, u32 r) { return (v << r) | (v >> (32u - r)); }

// JAX partitionable threefry, key=(0,1), ctr=(0,j), bits=o0^o1.
// Verified bit-exact (R1-R5 absmax 0). DO NOT TOUCH.
__device__ __forceinline__ u32 threefry_bits(u32 j) {
    const u32 ks0 = 0u, ks1 = 1u, ks2 = 0x1BD11BDBu;
    u32 x0 = ks0, x1 = j + ks1;
    x0 += x1; x1 = rotl32(x1, 13); x1 ^= x0;
    x0 += x1; x1 = rotl32(x1, 15); x1 ^= x0;
    x0 += x1; x1 = rotl32(x1, 26); x1 ^= x0;
    x0 += x1; x1 = rotl32(x1, 6);  x1 ^= x0;
    x0 += ks1; x1 += ks2 + 1u;
    x0 += x1; x1 = rotl32(x1, 17); x1 ^= x0;
    x0 += x1; x1 = rotl32(x1, 29); x1 ^= x0;
    x0 += x1; x1 = rotl32(x1, 16); x1 ^= x0;
    x0 += x1; x1 = rotl32(x1, 24); x1 ^= x0;
    x0 += ks2; x1 += ks0 + 2u;
    x0 += x1; x1 = rotl32(x1, 13); x1 ^= x0;
    x0 += x1; x1 = rotl32(x1, 15); x1 ^= x0;
    x0 += x1; x1 = rotl32(x1, 26); x1 ^= x0;
    x0 += x1; x1 = rotl32(x1, 6);  x1 ^= x0;
    x0 += ks0; x1 += ks1 + 3u;
    x0 += x1; x1 = rotl32(x1, 17); x1 ^= x0;
    x0 += x1; x1 = rotl32(x1, 29); x1 ^= x0;
    x0 += x1; x1 = rotl32(x1, 16); x1 ^= x0;
    x0 += x1; x1 = rotl32(x1, 24); x1 ^= x0;
    x0 += ks1; x1 += ks2 + 4u;
    x0 += x1; x1 = rotl32(x1, 13); x1 ^= x0;
    x0 += x1; x1 = rotl32(x1, 15); x1 ^= x0;
    x0 += x1; x1 = rotl32(x1, 26); x1 ^= x0;
    x0 += x1; x1 = rotl32(x1, 6);  x1 ^= x0;
    x0 += ks2; x1 += ks0 + 5u;
    return x0 ^ x1;
}

__device__ __forceinline__ float q_of(float x, float invT, float xm) {
    return __expf(fmaf(x, invT, -xm));
}

__device__ __forceinline__ float noise_of(u32 j) {
    u32 bits = threefry_bits(j);
    float u = __uint_as_float((bits >> 9) | 0x3F800000u) - 1.0f;
    return fmaxf(-log1pf(-u), 1e-10f);
}

// =====================================================================
// Monolithic per-row sampler: one block (1024 thr) per row.
//   A: max+argmax (HBM pass)          -- verbatim k1/fallback semantics
//   B: u64 fixed-point LDS histogram  -- verbatim k2 arithmetic (L3-hot)
//      + suffix scan / cut / thr      -- verbatim k3 arithmetic
//   C: filter -> per-wave register-offset compaction -> dense threefry
//      (no LDS atomics / shfl broadcasts in the compaction path)
//   D: bitonic sort + exact cut + final race          -- verbatim k5
// All global intermediates (Whist/Wcnt/Wlist/Wwin/RowPar) eliminated.
// =====================================================================
extern "C" __global__ void __launch_bounds__(1024, 1)
sampler_mono(const float* __restrict__ logits, const float* __restrict__ temps,
             const float* __restrict__ topps, int* __restrict__ out)
{
    const int r = blockIdx.x;
    const int tid = threadIdx.x, lane = tid & 63, wid = tid >> 6;
    const float4* L4 = (const float4*)(logits + (size_t)r * VV);

    // 48 KB LDS, phase-overlaid:
    //   phase B: hist u64[4096]                (32 KB, first region)
    //   phase C: queue u64[16][256]            (32 KB, first region)
    //            sortbuf u64[2048]             (16 KB, second region)
    __shared__ __align__(16) unsigned char SMEM[49152];
    u64* hist    = (u64*)SMEM;
    u64* queue   = (u64*)SMEM;
    u64* sortbuf = (u64*)(SMEM + 32768);

    __shared__ double wtot[16];
    __shared__ float wredf[16];
    __shared__ int wredi[16];
    __shared__ u64 wredu[16];
    __shared__ int qcnt[16];
    __shared__ float sh_rm, sh_thr;
    __shared__ int sh_gidx, sh_bstar, sh_ng, sh_js;
    __shared__ double sh_cutZ, sh_M;

    const float Traw = temps[r];
    const float T = fmaxf(Traw, 1e-5f);
    const float invT = 1.0f / T;

    // ---------------- Phase A: row max + argmax ----------------
    float m = -3.402823466e38f; int mi = 0x7FFFFFFF;
    auto upd = [&](float4 a, int iv) {
        float m4 = fmaxf(fmaxf(a.x, a.y), fmaxf(a.z, a.w));
        if (m4 > m) {                    // strict > keeps first occurrence
            int base = iv * 4;
            if      (a.x == m4) mi = base;
            else if (a.y == m4) mi = base + 1;
            else if (a.z == m4) mi = base + 2;
            else                mi = base + 3;
            m = m4;
        }
    };
    #pragma unroll 1
    for (int it = 0; it < 7; ++it) {     // ascending iv order (tie semantics)
        int iv = tid + it * 4096;
        float4 a0 = L4[iv], a1 = L4[iv + 1024], a2 = L4[iv + 2048], a3 = L4[iv + 3072];
        upd(a0, iv); upd(a1, iv + 1024); upd(a2, iv + 2048); upd(a3, iv + 3072);
    }
    {
        int iv = tid + 28672;            // 3 full strides + 256-tail
        bool h3v = tid < 256;
        float4 a0 = L4[iv], a1 = L4[iv + 1024], a2 = L4[iv + 2048];
        float4 a3 = L4[h3v ? iv + 3072 : iv];
        upd(a0, iv); upd(a1, iv + 1024); upd(a2, iv + 2048);
        if (h3v) upd(a3, iv + 3072);
    }
    for (int off = 32; off; off >>= 1) {
        float ov = __shfl_down(m, off); int oi = __shfl_down(mi, off);
        if (ov > m || (ov == m && oi < mi)) { m = ov; mi = oi; }
    }
    if (lane == 0) { wredf[wid] = m; wredi[wid] = mi; }
    // zero hist + init control while waiting
    for (int i = tid; i < NBUCK; i += 1024) hist[i] = 0ULL;
    if (tid == 0) { sh_ng = 0; sh_js = 0x7FFFFFFF; }
    __syncthreads();
    if (wid == 0) {
        float v = (lane < 16) ? wredf[lane] : -3.402823466e38f;
        int   i = (lane < 16) ? wredi[lane] : 0x7FFFFFFF;
        for (int off = 32; off; off >>= 1) {
            float ov = __shfl_down(v, off);
            int   oi = __shfl_down(i, off);
            if (ov > v || (ov == v && oi < i)) { v = ov; i = oi; }
        }
        if (lane == 0) { sh_rm = v; sh_gidx = i; }
    }
    __syncthreads();
    const float rm = sh_rm;
    const float xm = rm * invT;

    // ---------------- Phase B: u64 fixed-point histogram ----------------
    auto proc = [&](float4 x) {
        float xs[4] = {x.x, x.y, x.z, x.w};
        #pragma unroll
        for (int k = 0; k < 4; k++) {
            float t = fmaf(xs[k], invT, -xm);
            if (t < -104.0f) continue;           // q bits would be exactly 0
            float q = __expf(t);
            u32 pb = __float_as_uint(q);
            if (pb) atomicAdd(&hist[pb >> 18], (u64)(q * QSCALE));
        }
    };
    #pragma unroll 1
    for (int it = 0; it < 7; ++it) {
        int iv = tid + it * 4096;
        float4 a0 = L4[iv], a1 = L4[iv + 1024], a2 = L4[iv + 2048], a3 = L4[iv + 3072];
        proc(a0); proc(a1); proc(a2); proc(a3);
    }
    {
        int iv = tid + 28672;
        bool h3v = tid < 256;
        float4 a0 = L4[iv], a1 = L4[iv + 1024], a2 = L4[iv + 2048];
        float4 a3 = L4[h3v ? iv + 3072 : iv];
        proc(a0); proc(a1); proc(a2);
        if (h3v) proc(a3);
    }
    __syncthreads();

    // ---------------- suffix scan + cut + thr (verbatim k3) ----------------
    {
        double h0 = (double)hist[4 * tid]     * QINV;
        double h1 = (double)hist[4 * tid + 1] * QINV;
        double h2 = (double)hist[4 * tid + 2] * QINV;
        double h3 = (double)hist[4 * tid + 3] * QINV;
        double s3 = h3, s2 = s3 + h2, s1 = s2 + h1, s0 = s1 + h0;
        double incl = s0;
        for (int off = 1; off < 64; off <<= 1) {
            double u = __shfl_down(incl, off);
            if (lane + off < 64) incl += u;
        }
        double excl = __shfl_down(incl, 1); if (lane == 63) excl = 0.0;
        if (lane == 0) wtot[wid] = incl;
        if (tid == 0) { sh_bstar = -1; sh_M = 0.0; }
        __syncthreads();
        double cw = 0.0;
        for (int w = wid + 1; w < 16; w++) cw += wtot[w];
        double carry = excl + cw;
        if (tid == 0) sh_cutZ = (double)topps[r] * (s0 + carry);
        __syncthreads();
        double cutZ = sh_cutZ;
        double S0 = s0 + carry, S1 = s1 + carry, S2 = s2 + carry, S3 = s3 + carry;
        if (S0 > cutZ && S1 <= cutZ)    { sh_bstar = 4 * tid;     sh_M = S1; }
        if (S1 > cutZ && S2 <= cutZ)    { sh_bstar = 4 * tid + 1; sh_M = S2; }
        if (S2 > cutZ && S3 <= cutZ)    { sh_bstar = 4 * tid + 2; sh_M = S3; }
        if (S3 > cutZ && carry <= cutZ) { sh_bstar = 4 * tid + 3; sh_M = carry; }
        __syncthreads();
        if (tid == 0) {
            // conservative t-threshold: bucket(q_of(t)) >= bstar  =>  t >= thr
            float thr = -3.402823466e38f;
            if (sh_bstar > 0) {
                float qlo = __uint_as_float((u32)sh_bstar << 18);
                if (qlo >= 1.17549435e-38f) thr = logf(qlo) - 1e-3f;
            }
            sh_thr = thr;
        }
    }
    __syncthreads();

    // ---------------- Phase C: filter -> per-wave compact -> dense race ----------------
    const int bstar = sh_bstar;
    const float thr = sh_thr;
    const double cutZ = sh_cutZ;
    const double M = sh_M;
    const u32 jbase = (u32)r * (u32)VV;
    const int wbase = wid << 8;          // wave's 256-entry queue segment
    u64 pk = 0ULL;

    float4 x = L4[tid];                  // prefetch chunk 0
    #pragma unroll 1
    for (int c = 0; c < 32; ++c) {
        bool valid = (c < 31) || (tid < 256);    // wave-uniform (256 = 4 waves)
        __syncthreads();                 // queue region free (prev dense / scan done)
        int wcount = 0;
        if (valid) {
            float t0 = fmaf(x.x, invT, -xm), t1 = fmaf(x.y, invT, -xm);
            float t2 = fmaf(x.z, invT, -xm), t3 = fmaf(x.w, invT, -xm);
            float ts[4] = {t0, t1, t2, t3};
            int base = (tid + c * 1024) * 4;
            #pragma unroll
            for (int k = 0; k < 4; k++) {
                bool pass = ts[k] >= thr;
                u64 bm = __ballot(pass);
                if (pass) {
                    int off = __popcll(bm & ((1ULL << lane) - 1ULL));
                    queue[wbase + wcount + off] =
                        ((u64)__float_as_uint(ts[k]) << 32) | (u32)(base + k);
                }
                wcount += __popcll(bm);
            }
        }
        if (lane == 0) qcnt[wid] = wcount;
        __syncthreads();
        if (c + 1 < 32) {                // prefetch next chunk under dense work
            int ivn = tid + (c + 1) * 1024;
            bool vn = (c + 1 < 31) || (tid < 256);
            x = L4[vn ? ivn : tid];
        }
        // dense sweep over all 16 wave segments (contiguous-from-0 per segment)
        for (int di = tid; di < 4096; di += 1024) {
            int w = di >> 8, l = di & 255;
            if (l < qcnt[w]) {
                u64 e = queue[(w << 8) + l];
                float tt = __uint_as_float((u32)(e >> 32));
                u32 v = (u32)e;
                float q = __expf(tt);
                u32 pb = __float_as_uint(q);
                if (pb) {
                    int b = (int)(pb >> 18);
                    if (b > bstar) {
                        float nz = noise_of(jbase + v);
                        float sc = __fdividef(q, nz);
                        u64 ee = ((u64)__float_as_uint(sc) << 32) | (u64)(~v);
                        if (ee > pk) pk = ee;
                    } else if (b == bstar) {
                        int pos = atomicAdd(&sh_ng, 1);
                        if (pos < CAP)
                            sortbuf[pos] = ((u64)pb << 32) | (u64)(~v);
                    }
                }
            }
        }
    }
    __syncthreads();

    // ---------------- Phase D: sort + exact cut + final race (verbatim k5) ----------------
    int n = sh_ng; if (n > CAP) n = CAP;
    int npad = 4; while (npad < n) npad <<= 1;
    for (int i = tid; i < npad; i += 1024) if (i >= n) sortbuf[i] = 0ULL;
    __syncthreads();
    for (int k = 2; k <= npad; k <<= 1) {
        for (int j = k >> 1; j > 0; j >>= 1) {
            for (int i = tid; i < npad; i += 1024) {
                int q2 = i ^ j;
                if (q2 > i) {
                    u64 a = sortbuf[i], b = sortbuf[q2];
                    bool desc = ((i & k) == 0);
                    if (desc ? (a < b) : (a > b)) { sortbuf[i] = b; sortbuf[q2] = a; }
                }
            }
            __syncthreads();
        }
    }
    {
        int t2 = tid * 2;
        double f0 = 0.0, f1 = 0.0;
        if (t2 < npad) {
            f0 = (double)__uint_as_float((u32)(sortbuf[t2] >> 32));
            f1 = (double)__uint_as_float((u32)(sortbuf[t2 + 1] >> 32));
        }
        double c0 = f0, c1 = c0 + f1;
        double incl = c1;
        for (int off = 1; off < 64; off <<= 1) {
            double u = __shfl_up(incl, off);
            if (lane >= off) incl += u;
        }
        double excl = __shfl_up(incl, 1); if (lane == 0) excl = 0.0;
        double wt = __shfl(incl, 63);
        if (lane == 0) wtot[wid] = wt;
        __syncthreads();
        double cw = 0.0;
        for (int w = 0; w < wid; w++) cw += wtot[w];
        double cr = cw + excl;
        if (t2 < npad) {
            bool m0 = (M + (cr + c0)) > cutZ;
            bool m1 = (M + (cr + c1)) > cutZ;
            int cand = m0 ? t2 : m1 ? (t2 + 1) : 0x7FFFFFFF;
            if (cand != 0x7FFFFFFF) atomicMin(&sh_js, cand);
        }
    }
    __syncthreads();
    if (tid == 0) {
        int js = sh_js; if (js > n) js = n;
        int btop = (int)(__float_as_uint(q_of(rm, invT, xm)) >> 18);
        if (js == 0 && bstar == btop) js = 1;    // mask[:,0]=False
        sh_js = js;
    }
    __syncthreads();
    int js = sh_js;
    for (int i = tid; i < js; i += 1024) {
        u64 key = sortbuf[i];
        float qq = __uint_as_float((u32)(key >> 32));
        u32 v = ~(u32)key;
        float nz = noise_of(jbase + v);
        float sc = __fdividef(qq, nz);
        u64 e = ((u64)__float_as_uint(sc) << 32) | (u64)(~v);
        if (e > pk) pk = e;
    }
    for (int off = 32; off; off >>= 1) { u64 o = __shfl_down(pk, off); if (o > pk) pk = o; }
    if (lane == 0) wredu[wid] = pk;
    __syncthreads();
    if (tid == 0) {
        for (int w = 1; w < 16; w++) if (wredu[w] > pk) pk = wredu[w];
        int bi = (int)(~(u32)pk);
        out[r] = (Traw <= 1e-10f) ? sh_gidx : bi;
    }
}

extern "C" void kernel_launch(void* const* d_in, const int* in_sizes, int n_in,
                              void* d_out, int out_size, void* d_ws, size_t ws_size,
                              hipStream_t stream) {
    const float* logits = (const float*)d_in[0];
    const float* temps = (const float*)d_in[1];
    const float* topps = (const float*)d_in[2];
    int* out = (int*)d_out;
    (void)in_sizes; (void)n_in; (void)out_size; (void)d_ws; (void)ws_size;
    sampler_mono<<<BB, 1024, 0, stream>>>(logits, temps, topps, out);
}

// Round 4
// 368.948 us; speedup vs baseline: 1.1327x; 1.1327x over previous
//
#include <hip/hip_runtime.h>
#include <stdint.h>

typedef unsigned long long u64;
typedef uint32_t u32;

#define BB 256
#define VV 128000
#define NV4 (VV / 4)          // 32000 float4 per row
#define SLICES 16
#define SL4 (NV4 / SLICES)    // 2000 float4 per slice
#define NBUCK 4096
#define CAP 2048
#define QSCALE 1.099511627776e12f   // 2^40 fixed-point scale for q
#define QINV   (1.0 / 1099511627776.0)

// ---- workspace layout (bytes) ----
#define OFF_SMAX 0                          // float[256*16]
#define OFF_SARG (16*1024)                  // int[256*16]
#define OFF_WWIN (32*1024)                  // u64[256*16]
#define OFF_PAR  (64*1024)                  // RowPar[256]
#define OFF_CNT  (72*1024)                  // int[256]   (zeroed by k1)
#define OFF_HIST (80*1024)                  // u64[256*4096] (zeroed by k1)
#define OFF_LIST (OFF_HIST + (size_t)BB*NBUCK*8)  // u64[256*CAP]
#define WS_TOTAL (OFF_LIST + (size_t)BB*CAP*8)

struct RowPar { int bstar; float thr; double M; double cutZ; };

#if defined(__has_builtin)
# if __has_builtin(__builtin_amdgcn_sched_barrier)
#  define SCHED_FENCE() __builtin_amdgcn_sched_barrier(0)
# endif
#endif
#ifndef SCHED_FENCE
# define SCHED_FENCE() asm volatile("" ::: "memory")
#endif

__device__ __forceinline__ u32 rotl32(u32 v, u32 r) { return (v << r) | (v >> (32u - r)); }

// JAX partitionable threefry, key=(0,1), ctr=(0,j), bits=o0^o1.
// Verified bit-exact (R1-R5 absmax 0). DO NOT TOUCH.
__device__ __forceinline__ u32 threefry_bits(u32 j) {
    const u32 ks0 = 0u, ks1 = 1u, ks2 = 0x1BD11BDBu;
    u32 x0 = ks0, x1 = j + ks1;
    x0 += x1; x1 = rotl32(x1, 13); x1 ^= x0;
    x0 += x1; x1 = rotl32(x1, 15); x1 ^= x0;
    x0 += x1; x1 = rotl32(x1, 26); x1 ^= x0;
    x0 += x1; x1 = rotl32(x1, 6);  x1 ^= x0;
    x0 += ks1; x1 += ks2 + 1u;
    x0 += x1; x1 = rotl32(x1, 17); x1 ^= x0;
    x0 += x1; x1 = rotl32(x1, 29); x1 ^= x0;
    x0 += x1; x1 = rotl32(x1, 16); x1 ^= x0;
    x0 += x1; x1 = rotl32(x1, 24); x1 ^= x0;
    x0 += ks2; x1 += ks0 + 2u;
    x0 += x1; x1 = rotl32(x1, 13); x1 ^= x0;
    x0 += x1; x1 = rotl32(x1, 15); x1 ^= x0;
    x0 += x1; x1 = rotl32(x1, 26); x1 ^= x0;
    x0 += x1; x1 = rotl32(x1, 6);  x1 ^= x0;
    x0 += ks0; x1 += ks1 + 3u;
    x0 += x1; x1 = rotl32(x1, 17); x1 ^= x0;
    x0 += x1; x1 = rotl32(x1, 29); x1 ^= x0;
    x0 += x1; x1 = rotl32(x1, 16); x1 ^= x0;
    x0 += x1; x1 = rotl32(x1, 24); x1 ^= x0;
    x0 += ks1; x1 += ks2 + 4u;
    x0 += x1; x1 = rotl32(x1, 13); x1 ^= x0;
    x0 += x1; x1 = rotl32(x1, 15); x1 ^= x0;
    x0 += x1; x1 = rotl32(x1, 26); x1 ^= x0;
    x0 += x1; x1 = rotl32(x1, 6);  x1 ^= x0;
    x0 += ks2; x1 += ks0 + 5u;
    return x0 ^ x1;
}

__device__ __forceinline__ float q_of(float x, float invT, float xm) {
    return __expf(fmaf(x, invT, -xm));
}

__device__ __forceinline__ float noise_of(u32 j) {
    u32 bits = threefry_bits(j);
    float u = __uint_as_float((bits >> 9) | 0x3F800000u) - 1.0f;
    return fmaxf(-log1pf(-u), 1e-10f);
}

// ---------------- K1: per-slice max/argmax + workspace zeroing ----------------
extern "C" __global__ void __launch_bounds__(256, 1)
k1_stats(const float* __restrict__ logits, float* __restrict__ smax,
         int* __restrict__ sarg, u64* __restrict__ Whist, int* __restrict__ Wcnt) {
    int blk = blockIdx.x, r = blk >> 4, s = blk & 15;
    int tid = threadIdx.x, lane = tid & 63, wid = tid >> 6;
    __shared__ float sf[4]; __shared__ int si[4];
    // zero this slice's chunk of the row hist + counter (replaces memsets)
    Whist[(size_t)r * NBUCK + s * 256 + tid] = 0ULL;
    if (s == 0 && tid == 0) Wcnt[r] = 0;
    const float4* L4 = (const float4*)(logits + (size_t)r * VV);
    int i0 = s * SL4 + tid;
    bool h7 = tid < (SL4 - 7 * 256);   // tid < 208
    float4 b0 = L4[i0],          b1 = L4[i0 + 256],  b2 = L4[i0 + 512];
    float4 b3 = L4[i0 + 768],    b4 = L4[i0 + 1024], b5 = L4[i0 + 1280];
    float4 b6 = L4[i0 + 1536],   b7 = L4[h7 ? i0 + 1792 : i0];
    SCHED_FENCE();                      // keep all 8 loads in flight (MLP=8)
    float m = -3.402823466e38f; int mi = 0x7FFFFFFF;
    auto upd = [&](float4 a, int iv) {
        float m4 = fmaxf(fmaxf(a.x, a.y), fmaxf(a.z, a.w));
        if (m4 > m) {                   // strict > keeps first occurrence
            int base = iv * 4;
            if      (a.x == m4) mi = base;
            else if (a.y == m4) mi = base + 1;
            else if (a.z == m4) mi = base + 2;
            else                mi = base + 3;
            m = m4;
        }
    };
    upd(b0, i0);        upd(b1, i0 + 256);  upd(b2, i0 + 512);  upd(b3, i0 + 768);
    upd(b4, i0 + 1024); upd(b5, i0 + 1280); upd(b6, i0 + 1536);
    if (h7) upd(b7, i0 + 1792);
    for (int off = 32; off; off >>= 1) {
        float ov = __shfl_down(m, off); int oi = __shfl_down(mi, off);
        if (ov > m || (ov == m && oi < mi)) { m = ov; mi = oi; }
    }
    if (lane == 0) { sf[wid] = m; si[wid] = mi; }
    __syncthreads();
    if (tid == 0) {
        for (int w = 1; w < 4; w++) {
            float ov = sf[w]; int oi = si[w];
            if (ov > m || (ov == m && oi < mi)) { m = ov; mi = oi; }
        }
        smax[blk] = m; sarg[blk] = mi;
    }
}

// -------- K2: u64 fixed-point LDS histogram (fast integer DS atomics) --------
extern "C" __global__ void __launch_bounds__(256, 1)
k2_hist(const float* __restrict__ logits, const float* __restrict__ smax,
        const float* __restrict__ temps, u64* __restrict__ Whist) {
    __shared__ u64 lh[NBUCK];           // 32 KB
    int blk = blockIdx.x, r = blk >> 4, s = blk & 15, tid = threadIdx.x;
    for (int i = tid; i < NBUCK; i += 256) lh[i] = 0ULL;
    float T = fmaxf(temps[r], 1e-5f), invT = 1.0f / T;
    float rm = -3.402823466e38f;
    for (int j = 0; j < 16; j++) rm = fmaxf(rm, smax[r * 16 + j]);
    float xm = rm * invT;
    __syncthreads();
    const float4* L4 = (const float4*)(logits + (size_t)r * VV);
    int i0 = s * SL4 + tid;
    bool h7 = tid < (SL4 - 7 * 256);
    float4 b0 = L4[i0],          b1 = L4[i0 + 256],  b2 = L4[i0 + 512];
    float4 b3 = L4[i0 + 768],    b4 = L4[i0 + 1024], b5 = L4[i0 + 1280];
    float4 b6 = L4[i0 + 1536],   b7 = L4[h7 ? i0 + 1792 : i0];
    SCHED_FENCE();
    auto proc = [&](float4 x) {
        float xs[4] = {x.x, x.y, x.z, x.w};
        #pragma unroll
        for (int k = 0; k < 4; k++) {
            float t = fmaf(xs[k], invT, -xm);
            if (t < -104.0f) continue;          // q bits would be exactly 0
            float q = __expf(t);
            u32 pb = __float_as_uint(q);
            if (pb) atomicAdd(&lh[pb >> 18], (u64)(q * QSCALE));
        }
    };
    proc(b0); proc(b1); proc(b2); proc(b3); proc(b4); proc(b5); proc(b6);
    if (h7) proc(b7);
    __syncthreads();
    u64* gh = Whist + (size_t)r * NBUCK;
    for (int i = tid; i < NBUCK; i += 256) {
        u64 v = lh[i];
        if (v) atomicAdd(&gh[i], v);
    }
}

// ---------------- K3: per-row suffix scan + cut + skip-threshold ----------------
extern "C" __global__ void __launch_bounds__(1024)
k3_cut(const u64* __restrict__ Whist, const float* __restrict__ topps,
       RowPar* __restrict__ par) {
    int r = blockIdx.x, tid = threadIdx.x, lane = tid & 63, wid = tid >> 6;
    __shared__ double wtot[16];
    __shared__ double sh_cutZ; __shared__ int sh_b; __shared__ double sh_M;
    const u64* gh = Whist + (size_t)r * NBUCK;
    double h0 = (double)gh[4 * tid]     * QINV;
    double h1 = (double)gh[4 * tid + 1] * QINV;
    double h2 = (double)gh[4 * tid + 2] * QINV;
    double h3 = (double)gh[4 * tid + 3] * QINV;
    double s3 = h3, s2 = s3 + h2, s1 = s2 + h1, s0 = s1 + h0;
    double incl = s0;
    for (int off = 1; off < 64; off <<= 1) {
        double u = __shfl_down(incl, off);
        if (lane + off < 64) incl += u;
    }
    double excl = __shfl_down(incl, 1); if (lane == 63) excl = 0.0;
    if (lane == 0) wtot[wid] = incl;
    if (tid == 0) { sh_b = -1; sh_M = 0.0; }
    __syncthreads();
    double cw = 0.0;
    for (int w = wid + 1; w < 16; w++) cw += wtot[w];
    double carry = excl + cw;
    if (tid == 0) sh_cutZ = (double)topps[r] * (s0 + carry);
    __syncthreads();
    double cutZ = sh_cutZ;
    double S0 = s0 + carry, S1 = s1 + carry, S2 = s2 + carry, S3 = s3 + carry;
    if (S0 > cutZ && S1 <= cutZ)    { sh_b = 4 * tid;     sh_M = S1; }
    if (S1 > cutZ && S2 <= cutZ)    { sh_b = 4 * tid + 1; sh_M = S2; }
    if (S2 > cutZ && S3 <= cutZ)    { sh_b = 4 * tid + 2; sh_M = S3; }
    if (S3 > cutZ && carry <= cutZ) { sh_b = 4 * tid + 3; sh_M = carry; }
    __syncthreads();
    if (tid == 0) {
        // conservative t-threshold: bucket(q_of(t)) >= bstar  =>  t >= thr
        float thr = -3.402823466e38f;
        if (sh_b > 0) {
            float qlo = __uint_as_float((u32)sh_b << 18);
            if (qlo >= 1.17549435e-38f) thr = logf(qlo) - 1e-3f;
        }
        RowPar p; p.bstar = sh_b; p.thr = thr; p.M = sh_M; p.cutZ = cutZ;
        par[r] = p;
    }
}

// -------- K4: filter -> per-wave private compact -> dense threefry race --------
// Wave-autonomous: each wave packs survivors (t-bits + index) into its own
// 256-entry LDS segment at register-computed prefix offsets, then immediately
// dense-processes its own count. No LDS atomics, no shfl broadcasts, and
// ZERO __syncthreads in the main loop (only lgkmcnt between write & read).
// expf deferred to the dense path (survivors only). Arithmetic identical to
// the verified mono phase C (R3, absmax 0).
extern "C" __global__ void __launch_bounds__(256, 1)
k4_race(const float* __restrict__ logits, const float* __restrict__ smax,
        const float* __restrict__ temps, const RowPar* __restrict__ par,
        int* __restrict__ Wcnt, u64* __restrict__ Wlist, u64* __restrict__ Wwin) {
    int blk = blockIdx.x, r = blk >> 4, s = blk & 15;
    int tid = threadIdx.x, lane = tid & 63, wid = tid >> 6;
    __shared__ u64 seg[4][256];          // 8 KB: per-wave survivor queue
    __shared__ u64 wred[4];
    float T = fmaxf(temps[r], 1e-5f), invT = 1.0f / T;
    float rm = -3.402823466e38f;
    for (int j = 0; j < 16; j++) rm = fmaxf(rm, smax[r * 16 + j]);
    float xm = rm * invT;
    int bstar = par[r].bstar;
    float thr = par[r].thr;
    const float4* L4 = (const float4*)(logits + (size_t)r * VV);
    u32 jbase = (u32)r * (u32)VV;
    u64 pk = 0ULL;
    const u64 lanelt = (1ULL << lane) - 1ULL;
    int i0 = s * SL4 + tid;
    bool h7 = tid < (SL4 - 7 * 256);
    float4 b0 = L4[i0],          b1 = L4[i0 + 256],  b2 = L4[i0 + 512];
    float4 b3 = L4[i0 + 768],    b4 = L4[i0 + 1024], b5 = L4[i0 + 1280];
    float4 b6 = L4[i0 + 1536],   b7 = L4[h7 ? i0 + 1792 : i0];
    SCHED_FENCE();                      // keep all 8 loads in flight (MLP=8)

    auto chunk = [&](float4 v, int iv, bool valid) {
        float t0 = fmaf(v.x, invT, -xm), t1 = fmaf(v.y, invT, -xm);
        float t2 = fmaf(v.z, invT, -xm), t3 = fmaf(v.w, invT, -xm);
        float ts[4] = {t0, t1, t2, t3};
        int base = iv * 4;
        int wcount = 0;
        #pragma unroll
        for (int k = 0; k < 4; k++) {
            bool pass = valid && (ts[k] >= thr);
            u64 bm = __ballot(pass);
            if (pass) {
                int off = __popcll(bm & lanelt);
                seg[wid][wcount + off] =
                    ((u64)__float_as_uint(ts[k]) << 32) | (u32)(base + k);
            }
            wcount += __popcll(bm);
        }
        asm volatile("s_waitcnt lgkmcnt(0)" ::: "memory");  // wave's writes visible
        for (int di = lane; di < wcount; di += 64) {
            u64 e = seg[wid][di];
            float tt = __uint_as_float((u32)(e >> 32));
            u32 dv = (u32)e;
            float q = __expf(tt);
            u32 pb = __float_as_uint(q);
            if (pb) {
                int b = (int)(pb >> 18);
                if (b > bstar) {
                    float nz = noise_of(jbase + dv);
                    float sc = __fdividef(q, nz);
                    u64 ee = ((u64)__float_as_uint(sc) << 32) | (u64)(~dv);
                    if (ee > pk) pk = ee;
                } else if (b == bstar) {
                    int pos = atomicAdd(&Wcnt[r], 1);
                    if (pos < CAP)
                        Wlist[(size_t)r * CAP + pos] = ((u64)pb << 32) | (u64)(~dv);
                }
            }
        }
    };
    chunk(b0, i0, true);        chunk(b1, i0 + 256, true);
    chunk(b2, i0 + 512, true);  chunk(b3, i0 + 768, true);
    chunk(b4, i0 + 1024, true); chunk(b5, i0 + 1280, true);
    chunk(b6, i0 + 1536, true); chunk(b7, i0 + 1792, h7);

    for (int off = 32; off; off >>= 1) { u64 o = __shfl_down(pk, off); if (o > pk) pk = o; }
    if (lane == 0) wred[wid] = pk;
    __syncthreads();
    if (tid == 0) {
        for (int w = 1; w < 4; w++) if (wred[w] > pk) pk = wred[w];
        Wwin[blk] = pk;
    }
}

// ---------------- K5: per-row sort + exact cut + final race/merge ----------------
extern "C" __global__ void __launch_bounds__(1024)
k5_final(const float* __restrict__ smax, const int* __restrict__ sarg,
         const float* __restrict__ temps, const float* __restrict__ topps,
         const RowPar* __restrict__ par, const int* __restrict__ Wcnt,
         const u64* __restrict__ Wlist, const u64* __restrict__ Wwin,
         int* __restrict__ out) {
    int r = blockIdx.x, tid = threadIdx.x, lane = tid & 63, wid = tid >> 6;
    __shared__ u64 sb[CAP];
    __shared__ double wtot[16];
    __shared__ u64 wred[16];
    __shared__ int sh_js, sh_n, sh_gidx; __shared__ float sh_rm;
    RowPar p = par[r];
    if (tid == 0) {
        float rm = -3.402823466e38f; int gi = 0x7FFFFFFF;
        for (int j = 0; j < 16; j++) {
            float v = smax[r * 16 + j];
            if (v > rm) { rm = v; gi = sarg[r * 16 + j]; }
        }
        sh_rm = rm; sh_gidx = gi;
        int n = Wcnt[r]; if (n > CAP) n = CAP; sh_n = n;
        sh_js = 0x7FFFFFFF;
    }
    __syncthreads();
    int n = sh_n;
    int npad = 4; while (npad < n) npad <<= 1;
    const u64* lst = Wlist + (size_t)r * CAP;
    for (int i = tid; i < npad; i += 1024) sb[i] = (i < n) ? lst[i] : 0ULL;
    __syncthreads();
    for (int k = 2; k <= npad; k <<= 1) {
        for (int j = k >> 1; j > 0; j >>= 1) {
            for (int i = tid; i < npad; i += 1024) {
                int q2 = i ^ j;
                if (q2 > i) {
                    u64 a = sb[i], b = sb[q2];
                    bool desc = ((i & k) == 0);
                    if (desc ? (a < b) : (a > b)) { sb[i] = b; sb[q2] = a; }
                }
            }
            __syncthreads();
        }
    }
    int t2 = tid * 2;
    double f0 = 0.0, f1 = 0.0;
    if (t2 < npad) {
        f0 = (double)__uint_as_float((u32)(sb[t2] >> 32));
        f1 = (double)__uint_as_float((u32)(sb[t2 + 1] >> 32));
    }
    double c0 = f0, c1 = c0 + f1;
    double incl = c1;
    for (int off = 1; off < 64; off <<= 1) {
        double u = __shfl_up(incl, off);
        if (lane >= off) incl += u;
    }
    double excl = __shfl_up(incl, 1); if (lane == 0) excl = 0.0;
    double wt = __shfl(incl, 63);
    if (lane == 0) wtot[wid] = wt;
    __syncthreads();
    double cw = 0.0;
    for (int w = 0; w < wid; w++) cw += wtot[w];
    double cr = cw + excl;
    if (t2 < npad) {
        bool m0 = (p.M + (cr + c0)) > p.cutZ;
        bool m1 = (p.M + (cr + c1)) > p.cutZ;
        int cand = m0 ? t2 : m1 ? (t2 + 1) : 0x7FFFFFFF;
        if (cand != 0x7FFFFFFF) atomicMin(&sh_js, cand);
    }
    __syncthreads();
    float Traw = temps[r];
    if (tid == 0) {
        int js = sh_js; if (js > n) js = n;
        float T = fmaxf(Traw, 1e-5f), invT = 1.0f / T, xm = sh_rm * invT;
        int btop = (int)(__float_as_uint(q_of(sh_rm, invT, xm)) >> 18);
        if (js == 0 && p.bstar == btop) js = 1;   // mask[:,0]=False
        sh_js = js;
    }
    __syncthreads();
    int js = sh_js;
    u32 jbase = (u32)r * (u32)VV;
    u64 pk = 0ULL;
    for (int i = tid; i < js; i += 1024) {
        u64 key = sb[i];
        float qq = __uint_as_float((u32)(key >> 32));
        u32 v = ~(u32)key;
        float nz = noise_of(jbase + v);
        float sc = __fdividef(qq, nz);
        u64 e = ((u64)__float_as_uint(sc) << 32) | (u64)(~v);
        if (e > pk) pk = e;
    }
    if (tid < 16) { u64 w = Wwin[r * 16 + tid]; if (w > pk) pk = w; }
    for (int off = 32; off; off >>= 1) { u64 o = __shfl_down(pk, off); if (o > pk) pk = o; }
    if (lane == 0) wred[wid] = pk;
    __syncthreads();
    if (tid == 0) {
        for (int w = 1; w < 16; w++) if (wred[w] > pk) pk = wred[w];
        int bi = (int)(~(u32)pk);
        out[r] = (Traw <= 1e-10f) ? sh_gidx : bi;
    }
}

// ---------------- fallback: verified R2 monolithic kernel ----------------
extern "C" __global__ void __launch_bounds__(1024, 1)
sampler_fallback(const float* __restrict__ logits, const float* __restrict__ temps,
                 const float* __restrict__ topps, int* __restrict__ out)
{
    const int row = blockIdx.x;
    const int tid = threadIdx.x;
    const int lane = tid & 63;
    const int wid = tid >> 6;
    const float* L = logits + (size_t)row * VV;
    const float4* L4 = (const float4*)L;
    __shared__ __align__(16) unsigned char SMEM[32768];
    float* hist = (float*)SMEM;
    u64* sortbuf = (u64*)SMEM;
    __shared__ double wtot[16];
    __shared__ float wredf[16];
    __shared__ int wredi[16];
    __shared__ float sh_lmax;
    __shared__ int sh_gidx;
    __shared__ double sh_cutZ;
    __shared__ double sh_M;
    __shared__ int sh_bstar;
    __shared__ int sh_ng;
    __shared__ int sh_jstar;
    const float Traw = temps[row];
    const float T = fmaxf(Traw, 1e-5f);
    const float invT = 1.0f / T;
    const float tp = topps[row];
    float lmax = -3.402823466e38f; int lidx = 0x7FFFFFFF;
    for (int iv = tid; iv < NV4; iv += 1024) {
        float4 x = L4[iv];
        float m4 = fmaxf(fmaxf(x.x, x.y), fmaxf(x.z, x.w));
        if (m4 > lmax) {
            int base = iv * 4;
            if      (x.x == m4) lidx = base;
            else if (x.y == m4) lidx = base + 1;
            else if (x.z == m4) lidx = base + 2;
            else                lidx = base + 3;
            lmax = m4;
        }
    }
    for (int off = 32; off > 0; off >>= 1) {
        float ov = __shfl_down(lmax, off);
        int   oi = __shfl_down(lidx, off);
        if (ov > lmax || (ov == lmax && oi < lidx)) { lmax = ov; lidx = oi; }
    }
    if (lane == 0) { wredf[wid] = lmax; wredi[wid] = lidx; }
    for (int i = tid; i < NBUCK; i += 1024) hist[i] = 0.0f;
    __syncthreads();
    if (wid == 0) {
        float v = (lane < 16) ? wredf[lane] : -3.402823466e38f;
        int   i = (lane < 16) ? wredi[lane] : 0x7FFFFFFF;
        for (int off = 32; off > 0; off >>= 1) {
            float ov = __shfl_down(v, off);
            int   oi = __shfl_down(i, off);
            if (ov > v || (ov == v && oi < i)) { v = ov; i = oi; }
        }
        if (lane == 0) { sh_lmax = v; sh_gidx = i; }
    }
    __syncthreads();
    const float xm = sh_lmax * invT;
    const int gidx = sh_gidx;
    const int btop = (int)(__float_as_uint(q_of(sh_lmax, invT, xm)) >> 18);
    for (int iv = tid; iv < NV4; iv += 1024) {
        float4 x = L4[iv];
        float q0 = q_of(x.x, invT, xm), q1 = q_of(x.y, invT, xm);
        float q2 = q_of(x.z, invT, xm), q3 = q_of(x.w, invT, xm);
        u32 b0 = __float_as_uint(q0), b1 = __float_as_uint(q1);
        u32 b2 = __float_as_uint(q2), b3 = __float_as_uint(q3);
        if (b0) atomicAdd(&hist[b0 >> 18], q0);
        if (b1) atomicAdd(&hist[b1 >> 18], q1);
        if (b2) atomicAdd(&hist[b2 >> 18], q2);
        if (b3) atomicAdd(&hist[b3 >> 18], q3);
    }
    __syncthreads();
    float h0 = hist[4 * tid], h1 = hist[4 * tid + 1],
          h2 = hist[4 * tid + 2], h3 = hist[4 * tid + 3];
    double s3 = (double)h3, s2 = s3 + (double)h2, s1 = s2 + (double)h1, s0 = s1 + (double)h0;
    double incl = s0;
    for (int off = 1; off < 64; off <<= 1) {
        double u = __shfl_down(incl, off);
        if (lane + off < 64) incl += u;
    }
    double excl = __shfl_down(incl, 1);
    if (lane == 63) excl = 0.0;
    if (lane == 0) wtot[wid] = incl;
    __syncthreads();
    double cw = 0.0;
    for (int w = wid + 1; w < 16; w++) cw += wtot[w];
    const double carry = excl + cw;
    if (tid == 0) {
        sh_cutZ = (double)tp * (s0 + carry);
        sh_bstar = -1; sh_M = 0.0; sh_ng = 0; sh_jstar = 0x7FFFFFFF;
    }
    __syncthreads();
    const double cutZ = sh_cutZ;
    {
        double S0 = s0 + carry, S1 = s1 + carry, S2 = s2 + carry, S3 = s3 + carry;
        if (S0 > cutZ && S1 <= cutZ)    { sh_bstar = 4 * tid;     sh_M = S1; }
        if (S1 > cutZ && S2 <= cutZ)    { sh_bstar = 4 * tid + 1; sh_M = S2; }
        if (S2 > cutZ && S3 <= cutZ)    { sh_bstar = 4 * tid + 2; sh_M = S3; }
        if (S3 > cutZ && carry <= cutZ) { sh_bstar = 4 * tid + 3; sh_M = carry; }
    }
    __syncthreads();
    const int bstar = sh_bstar;
    const double M = sh_M;
    float bs = -1.0f; int bi = 0x7FFFFFFF;
    const u32 jbase = (u32)row * (u32)VV;
    for (int iv = tid; iv < NV4; iv += 1024) {
        float4 x = L4[iv];
        float qs[4] = {q_of(x.x, invT, xm), q_of(x.y, invT, xm),
                       q_of(x.z, invT, xm), q_of(x.w, invT, xm)};
        int base = iv * 4;
        #pragma unroll
        for (int k = 0; k < 4; k++) {
            u32 pb = __float_as_uint(qs[k]);
            if (pb == 0u) continue;
            int b = (int)(pb >> 18);
            if (b > bstar) {
                int v = base + k;
                float nz = noise_of(jbase + (u32)v);
                float sc = __fdividef(qs[k], nz);
                if (sc > bs || (sc == bs && v < bi)) { bs = sc; bi = v; }
            } else if (b == bstar) {
                int pos = atomicAdd(&sh_ng, 1);
                if (pos < 4096)
                    sortbuf[pos] = ((u64)pb << 32) | (u32)(~(u32)(base + k));
            }
        }
    }
    __syncthreads();
    if (bstar >= 0) {
        int n = sh_ng; if (n > 4096) n = 4096;
        int npad = 4; while (npad < n) npad <<= 1;
        for (int i = tid; i < npad; i += 1024) if (i >= n) sortbuf[i] = 0ULL;
        __syncthreads();
        for (int k = 2; k <= npad; k <<= 1) {
            for (int j = k >> 1; j > 0; j >>= 1) {
                for (int i = tid; i < npad; i += 1024) {
                    int pidx = i ^ j;
                    if (pidx > i) {
                        u64 a = sortbuf[i], b2 = sortbuf[pidx];
                        bool desc = ((i & k) == 0);
                        if (desc ? (a < b2) : (a > b2)) { sortbuf[i] = b2; sortbuf[pidx] = a; }
                    }
                }
                __syncthreads();
            }
        }
        double f0 = 0.0, f1 = 0.0, f2 = 0.0, f3 = 0.0;
        int t4 = tid * 4;
        if (t4 < npad) {
            f0 = (double)__uint_as_float((u32)(sortbuf[t4]     >> 32));
            f1 = (double)__uint_as_float((u32)(sortbuf[t4 + 1] >> 32));
            f2 = (double)__uint_as_float((u32)(sortbuf[t4 + 2] >> 32));
            f3 = (double)__uint_as_float((u32)(sortbuf[t4 + 3] >> 32));
        }
        double c0 = f0, c1 = c0 + f1, c2 = c1 + f2, c3 = c2 + f3;
        double incl2 = c3;
        for (int off = 1; off < 64; off <<= 1) {
            double u = __shfl_up(incl2, off);
            if (lane >= off) incl2 += u;
        }
        double excl2 = __shfl_up(incl2, 1);
        if (lane == 0) excl2 = 0.0;
        double wt = __shfl(incl2, 63);
        if (lane == 0) wtot[wid] = wt;
        __syncthreads();
        double cw2 = 0.0;
        for (int w = 0; w < wid; w++) cw2 += wtot[w];
        double cr = cw2 + excl2;
        if (t4 < npad) {
            bool m0 = (M + (cr + c0)) > cutZ;
            bool m1 = (M + (cr + c1)) > cutZ;
            bool m2 = (M + (cr + c2)) > cutZ;
            bool m3 = (M + (cr + c3)) > cutZ;
            int cand = m0 ? t4 : m1 ? (t4 + 1) : m2 ? (t4 + 2) : m3 ? (t4 + 3) : 0x7FFFFFFF;
            if (cand != 0x7FFFFFFF) atomicMin(&sh_jstar, cand);
        }
        __syncthreads();
        int jstar = sh_jstar; if (jstar > n) jstar = n;
        if (jstar == 0 && bstar == btop) jstar = 1;
        for (int i = tid; i < jstar; i += 1024) {
            u64 key = sortbuf[i];
            float qq = __uint_as_float((u32)(key >> 32));
            int v = (int)(~(u32)key);
            float nz = noise_of(jbase + (u32)v);
            float sc = __fdividef(qq, nz);
            if (sc > bs || (sc == bs && v < bi)) { bs = sc; bi = v; }
        }
    }
    for (int off = 32; off > 0; off >>= 1) {
        float ov = __shfl_down(bs, off);
        int   oi = __shfl_down(bi, off);
        if (ov > bs || (ov == bs && oi < bi)) { bs = ov; bi = oi; }
    }
    if (lane == 0) { wredf[wid] = bs; wredi[wid] = bi; }
    __syncthreads();
    if (tid == 0) {
        float v = wredf[0]; int i = wredi[0];
        for (int w = 1; w < 16; w++) {
            float ov = wredf[w]; int oi = wredi[w];
            if (ov > v || (ov == v && oi < i)) { v = ov; i = oi; }
        }
        out[row] = (Traw <= 1e-10f) ? gidx : i;
    }
}

extern "C" void kernel_launch(void* const* d_in, const int* in_sizes, int n_in,
                              void* d_out, int out_size, void* d_ws, size_t ws_size,
                              hipStream_t stream) {
    const float* logits = (const float*)d_in[0];
    const float* temps = (const float*)d_in[1];
    const float* topps = (const float*)d_in[2];
    int* out = (int*)d_out;
    (void)in_sizes; (void)n_in; (void)out_size;

    if (ws_size >= WS_TOTAL) {
        char* ws = (char*)d_ws;
        float* smax  = (float*)(ws + OFF_SMAX);
        int*   sarg  = (int*)(ws + OFF_SARG);
        u64*   wwin  = (u64*)(ws + OFF_WWIN);
        RowPar* par  = (RowPar*)(ws + OFF_PAR);
        int*   wcnt  = (int*)(ws + OFF_CNT);
        u64*   whist = (u64*)(ws + OFF_HIST);
        u64*   wlist = (u64*)(ws + OFF_LIST);
        k1_stats<<<BB * SLICES, 256, 0, stream>>>(logits, smax, sarg, whist, wcnt);
        k2_hist<<<BB * SLICES, 256, 0, stream>>>(logits, smax, temps, whist);
        k3_cut<<<BB, 1024, 0, stream>>>(whist, topps, par);
        k4_race<<<BB * SLICES, 256, 0, stream>>>(logits, smax, temps, par, wcnt, wlist, wwin);
        k5_final<<<BB, 1024, 0, stream>>>(smax, sarg, temps, topps, par, wcnt, wlist, wwin, out);
    } else {
        sampler_fallback<<<BB, 1024, 0, stream>>>(logits, temps, topps, out);
    }
}

// Round 5
// 348.175 us; speedup vs baseline: 1.2003x; 1.0597x over previous
//
#include <hip/hip_runtime.h>
#include <stdint.h>

typedef unsigned long long u64;
typedef uint32_t u32;

#define BB 256
#define VV 128000
#define NV4 (VV / 4)          // 32000 float4 per row
#define SLICES 16
#define SL4 (NV4 / SLICES)    // 2000 float4 per slice
#define NBUCK 4096
#define CAP 2048
#define QSCALE 1.099511627776e12f   // 2^40 fixed-point scale for q
#define QINV   (1.0 / 1099511627776.0)

// ---- workspace layout (bytes) ----
#define OFF_SMAX 0                          // float[256*16]
#define OFF_SARG (16*1024)                  // int[256*16]
#define OFF_WWIN (32*1024)                  // u64[256*16]
#define OFF_PAR  (64*1024)                  // RowPar[256]
#define OFF_CNT  (72*1024)                  // int[256]   (zeroed by k1)
#define OFF_HIST (80*1024)                  // u64[256*4096] (zeroed by k1)
#define OFF_LIST (OFF_HIST + (size_t)BB*NBUCK*8)  // u64[256*CAP]
#define WS_TOTAL (OFF_LIST + (size_t)BB*CAP*8)

struct RowPar { int bstar; float thr; double M; double cutZ; };

#if defined(__has_builtin)
# if __has_builtin(__builtin_amdgcn_sched_barrier)
#  define SCHED_FENCE() __builtin_amdgcn_sched_barrier(0)
# endif
#endif
#ifndef SCHED_FENCE
# define SCHED_FENCE() asm volatile("" ::: "memory")
#endif

__device__ __forceinline__ u32 rotl32(u32 v, u32 r) { return (v << r) | (v >> (32u - r)); }

// JAX partitionable threefry, key=(0,1), ctr=(0,j), bits=o0^o1.
// Verified bit-exact (R1-R5 absmax 0). DO NOT TOUCH.
__device__ __forceinline__ u32 threefry_bits(u32 j) {
    const u32 ks0 = 0u, ks1 = 1u, ks2 = 0x1BD11BDBu;
    u32 x0 = ks0, x1 = j + ks1;
    x0 += x1; x1 = rotl32(x1, 13); x1 ^= x0;
    x0 += x1; x1 = rotl32(x1, 15); x1 ^= x0;
    x0 += x1; x1 = rotl32(x1, 26); x1 ^= x0;
    x0 += x1; x1 = rotl32(x1, 6);  x1 ^= x0;
    x0 += ks1; x1 += ks2 + 1u;
    x0 += x1; x1 = rotl32(x1, 17); x1 ^= x0;
    x0 += x1; x1 = rotl32(x1, 29); x1 ^= x0;
    x0 += x1; x1 = rotl32(x1, 16); x1 ^= x0;
    x0 += x1; x1 = rotl32(x1, 24); x1 ^= x0;
    x0 += ks2; x1 += ks0 + 2u;
    x0 += x1; x1 = rotl32(x1, 13); x1 ^= x0;
    x0 += x1; x1 = rotl32(x1, 15); x1 ^= x0;
    x0 += x1; x1 = rotl32(x1, 26); x1 ^= x0;
    x0 += x1; x1 = rotl32(x1, 6);  x1 ^= x0;
    x0 += ks0; x1 += ks1 + 3u;
    x0 += x1; x1 = rotl32(x1, 17); x1 ^= x0;
    x0 += x1; x1 = rotl32(x1, 29); x1 ^= x0;
    x0 += x1; x1 = rotl32(x1, 16); x1 ^= x0;
    x0 += x1; x1 = rotl32(x1, 24); x1 ^= x0;
    x0 += ks1; x1 += ks2 + 4u;
    x0 += x1; x1 = rotl32(x1, 13); x1 ^= x0;
    x0 += x1; x1 = rotl32(x1, 15); x1 ^= x0;
    x0 += x1; x1 = rotl32(x1, 26); x1 ^= x0;
    x0 += x1; x1 = rotl32(x1, 6);  x1 ^= x0;
    x0 += ks2; x1 += ks0 + 5u;
    return x0 ^ x1;
}

__device__ __forceinline__ float q_of(float x, float invT, float xm) {
    return __expf(fmaf(x, invT, -xm));
}

__device__ __forceinline__ float noise_of(u32 j) {
    u32 bits = threefry_bits(j);
    float u = __uint_as_float((bits >> 9) | 0x3F800000u) - 1.0f;
    return fmaxf(-log1pf(-u), 1e-10f);
}

// ---------------- K1: per-slice max/argmax + workspace zeroing ----------------
extern "C" __global__ void __launch_bounds__(256, 1)
k1_stats(const float* __restrict__ logits, float* __restrict__ smax,
         int* __restrict__ sarg, u64* __restrict__ Whist, int* __restrict__ Wcnt) {
    int blk = blockIdx.x, r = blk >> 4, s = blk & 15;
    int tid = threadIdx.x, lane = tid & 63, wid = tid >> 6;
    __shared__ float sf[4]; __shared__ int si[4];
    // zero this slice's chunk of the row hist + counter (replaces memsets)
    Whist[(size_t)r * NBUCK + s * 256 + tid] = 0ULL;
    if (s == 0 && tid == 0) Wcnt[r] = 0;
    const float4* L4 = (const float4*)(logits + (size_t)r * VV);
    int i0 = s * SL4 + tid;
    bool h7 = tid < (SL4 - 7 * 256);   // tid < 208
    float4 b0 = L4[i0],          b1 = L4[i0 + 256],  b2 = L4[i0 + 512];
    float4 b3 = L4[i0 + 768],    b4 = L4[i0 + 1024], b5 = L4[i0 + 1280];
    float4 b6 = L4[i0 + 1536],   b7 = L4[h7 ? i0 + 1792 : i0];
    SCHED_FENCE();                      // keep all 8 loads in flight (MLP=8)
    float m = -3.402823466e38f; int mi = 0x7FFFFFFF;
    auto upd = [&](float4 a, int iv) {
        float m4 = fmaxf(fmaxf(a.x, a.y), fmaxf(a.z, a.w));
        if (m4 > m) {                   // strict > keeps first occurrence
            int base = iv * 4;
            if      (a.x == m4) mi = base;
            else if (a.y == m4) mi = base + 1;
            else if (a.z == m4) mi = base + 2;
            else                mi = base + 3;
            m = m4;
        }
    };
    upd(b0, i0);        upd(b1, i0 + 256);  upd(b2, i0 + 512);  upd(b3, i0 + 768);
    upd(b4, i0 + 1024); upd(b5, i0 + 1280); upd(b6, i0 + 1536);
    if (h7) upd(b7, i0 + 1792);
    for (int off = 32; off; off >>= 1) {
        float ov = __shfl_down(m, off); int oi = __shfl_down(mi, off);
        if (ov > m || (ov == m && oi < mi)) { m = ov; mi = oi; }
    }
    if (lane == 0) { sf[wid] = m; si[wid] = mi; }
    __syncthreads();
    if (tid == 0) {
        for (int w = 1; w < 4; w++) {
            float ov = sf[w]; int oi = si[w];
            if (ov > m || (ov == m && oi < mi)) { m = ov; mi = oi; }
        }
        smax[blk] = m; sarg[blk] = mi;
    }
}

// -------- K2: u64 fixed-point LDS histogram (fast integer DS atomics) --------
extern "C" __global__ void __launch_bounds__(256, 1)
k2_hist(const float* __restrict__ logits, const float* __restrict__ smax,
        const float* __restrict__ temps, u64* __restrict__ Whist) {
    __shared__ u64 lh[NBUCK];           // 32 KB
    int blk = blockIdx.x, r = blk >> 4, s = blk & 15, tid = threadIdx.x;
    for (int i = tid; i < NBUCK; i += 256) lh[i] = 0ULL;
    float T = fmaxf(temps[r], 1e-5f), invT = 1.0f / T;
    float rm = -3.402823466e38f;
    for (int j = 0; j < 16; j++) rm = fmaxf(rm, smax[r * 16 + j]);
    float xm = rm * invT;
    __syncthreads();
    const float4* L4 = (const float4*)(logits + (size_t)r * VV);
    int i0 = s * SL4 + tid;
    bool h7 = tid < (SL4 - 7 * 256);
    float4 b0 = L4[i0],          b1 = L4[i0 + 256],  b2 = L4[i0 + 512];
    float4 b3 = L4[i0 + 768],    b4 = L4[i0 + 1024], b5 = L4[i0 + 1280];
    float4 b6 = L4[i0 + 1536],   b7 = L4[h7 ? i0 + 1792 : i0];
    SCHED_FENCE();
    auto proc = [&](float4 x) {
        float xs[4] = {x.x, x.y, x.z, x.w};
        #pragma unroll
        for (int k = 0; k < 4; k++) {
            float t = fmaf(xs[k], invT, -xm);
            // Bit-exact early-skip: for t < -27.7259 (= -40*ln2),
            // (u64)(q*QSCALE) == 0, so the atomicAdd was a no-op.
            // -27.75 leaves margin for expf ulp error. Saves expf+DS-atomic.
            if (t < -27.75f) continue;
            float q = __expf(t);
            u32 pb = __float_as_uint(q);
            if (pb) atomicAdd(&lh[pb >> 18], (u64)(q * QSCALE));
        }
    };
    proc(b0); proc(b1); proc(b2); proc(b3); proc(b4); proc(b5); proc(b6);
    if (h7) proc(b7);
    __syncthreads();
    u64* gh = Whist + (size_t)r * NBUCK;
    for (int i = tid; i < NBUCK; i += 256) {
        u64 v = lh[i];
        if (v) atomicAdd(&gh[i], v);
    }
}

// ---------------- K3: per-row suffix scan + cut + skip-threshold ----------------
extern "C" __global__ void __launch_bounds__(1024)
k3_cut(const u64* __restrict__ Whist, const float* __restrict__ topps,
       RowPar* __restrict__ par) {
    int r = blockIdx.x, tid = threadIdx.x, lane = tid & 63, wid = tid >> 6;
    __shared__ double wtot[16];
    __shared__ double sh_cutZ; __shared__ int sh_b; __shared__ double sh_M;
    const u64* gh = Whist + (size_t)r * NBUCK;
    double h0 = (double)gh[4 * tid]     * QINV;
    double h1 = (double)gh[4 * tid + 1] * QINV;
    double h2 = (double)gh[4 * tid + 2] * QINV;
    double h3 = (double)gh[4 * tid + 3] * QINV;
    double s3 = h3, s2 = s3 + h2, s1 = s2 + h1, s0 = s1 + h0;
    double incl = s0;
    for (int off = 1; off < 64; off <<= 1) {
        double u = __shfl_down(incl, off);
        if (lane + off < 64) incl += u;
    }
    double excl = __shfl_down(incl, 1); if (lane == 63) excl = 0.0;
    if (lane == 0) wtot[wid] = incl;
    if (tid == 0) { sh_b = -1; sh_M = 0.0; }
    __syncthreads();
    double cw = 0.0;
    for (int w = wid + 1; w < 16; w++) cw += wtot[w];
    double carry = excl + cw;
    if (tid == 0) sh_cutZ = (double)topps[r] * (s0 + carry);
    __syncthreads();
    double cutZ = sh_cutZ;
    double S0 = s0 + carry, S1 = s1 + carry, S2 = s2 + carry, S3 = s3 + carry;
    if (S0 > cutZ && S1 <= cutZ)    { sh_b = 4 * tid;     sh_M = S1; }
    if (S1 > cutZ && S2 <= cutZ)    { sh_b = 4 * tid + 1; sh_M = S2; }
    if (S2 > cutZ && S3 <= cutZ)    { sh_b = 4 * tid + 2; sh_M = S3; }
    if (S3 > cutZ && carry <= cutZ) { sh_b = 4 * tid + 3; sh_M = carry; }
    __syncthreads();
    if (tid == 0) {
        // conservative t-threshold: bucket(q_of(t)) >= bstar  =>  t >= thr
        float thr = -3.402823466e38f;
        if (sh_b > 0) {
            float qlo = __uint_as_float((u32)sh_b << 18);
            if (qlo >= 1.17549435e-38f) thr = logf(qlo) - 1e-3f;
        }
        RowPar p; p.bstar = sh_b; p.thr = thr; p.M = sh_M; p.cutZ = cutZ;
        par[r] = p;
    }
}

// -------- K4: R2 schedule + register-prefix per-wave compaction --------
// Keeps R2's proven structure (8 chunks, double-buffered LDS, block-balanced
// dense sweep, barrier per phase) but removes the 32 serialized
// {ballot -> LDS-atomic -> shfl-broadcast} chains: 4 independent ballots per
// chunk, per-wave private segment, offsets from register popcll prefixes
// (R4-validated bit-exact), plain qn store. expf deferred to the dense path
// (survivors only, R4-validated).
extern "C" __global__ void __launch_bounds__(256, 1)
k4_race(const float* __restrict__ logits, const float* __restrict__ smax,
        const float* __restrict__ temps, const RowPar* __restrict__ par,
        int* __restrict__ Wcnt, u64* __restrict__ Wlist, u64* __restrict__ Wwin) {
    int blk = blockIdx.x, r = blk >> 4, s = blk & 15;
    int tid = threadIdx.x, lane = tid & 63, wid = tid >> 6;
    __shared__ u64 seg[2][4][256];      // 16 KB: double-buffered per-wave queues
    __shared__ int qn[2][4];
    __shared__ u64 wred[4];
    float T = fmaxf(temps[r], 1e-5f), invT = 1.0f / T;
    float rm = -3.402823466e38f;
    for (int j = 0; j < 16; j++) rm = fmaxf(rm, smax[r * 16 + j]);
    float xm = rm * invT;
    int bstar = par[r].bstar;
    float thr = par[r].thr;
    const float4* L4 = (const float4*)(logits + (size_t)r * VV);
    u32 jbase = (u32)r * (u32)VV;
    u64 pk = 0ULL;
    const u64 lanelt = (1ULL << lane) - 1ULL;
    const int dsg = tid & 3, idxb = tid >> 2;   // dense-sweep coords (R2-balance)
    int i0 = s * SL4 + tid;
    bool h7 = tid < (SL4 - 7 * 256);
    float4 b0 = L4[i0],          b1 = L4[i0 + 256],  b2 = L4[i0 + 512];
    float4 b3 = L4[i0 + 768],    b4 = L4[i0 + 1024], b5 = L4[i0 + 1280];
    float4 b6 = L4[i0 + 1536],   b7 = L4[h7 ? i0 + 1792 : i0];
    SCHED_FENCE();                      // keep all 8 loads in flight (MLP=8)

    auto kfilter = [&](int ph, float4 v, int off, bool valid) {
        float t0 = fmaf(v.x, invT, -xm), t1 = fmaf(v.y, invT, -xm);
        float t2 = fmaf(v.z, invT, -xm), t3 = fmaf(v.w, invT, -xm);
        int base = (i0 + off) * 4;
        bool p0 = valid && (t0 >= thr), p1 = valid && (t1 >= thr);
        bool p2 = valid && (t2 >= thr), p3 = valid && (t3 >= thr);
        u64 m0 = __ballot(p0), m1 = __ballot(p1);
        u64 m2 = __ballot(p2), m3 = __ballot(p3);
        int c0 = __popcll(m0), c01 = c0 + __popcll(m1), c012 = c01 + __popcll(m2);
        u64* sg = seg[ph][wid];
        if (p0) sg[       __popcll(m0 & lanelt)] = ((u64)__float_as_uint(t0) << 32) | (u32)(base + 0);
        if (p1) sg[c0   + __popcll(m1 & lanelt)] = ((u64)__float_as_uint(t1) << 32) | (u32)(base + 1);
        if (p2) sg[c01  + __popcll(m2 & lanelt)] = ((u64)__float_as_uint(t2) << 32) | (u32)(base + 2);
        if (p3) sg[c012 + __popcll(m3 & lanelt)] = ((u64)__float_as_uint(t3) << 32) | (u32)(base + 3);
        if (lane == 0) qn[ph][wid] = c012 + __popcll(m3);
    };
    auto kproc = [&](u64 e) {
        float tt = __uint_as_float((u32)(e >> 32));
        u32 dv = (u32)e;
        float q = __expf(tt);
        u32 pb = __float_as_uint(q);
        if (pb) {
            int b = (int)(pb >> 18);
            if (b > bstar) {
                float nz = noise_of(jbase + dv);
                float sc = __fdividef(q, nz);
                u64 ee = ((u64)__float_as_uint(sc) << 32) | (u64)(~dv);
                if (ee > pk) pk = ee;
            } else if (b == bstar) {
                int pos = atomicAdd(&Wcnt[r], 1);
                if (pos < CAP)
                    Wlist[(size_t)r * CAP + pos] = ((u64)pb << 32) | (u64)(~dv);
            }
        }
    };
    auto kdense = [&](int ph) {
        int cnt = qn[ph][dsg];
        const u64* sg = seg[ph][dsg];
        u64 e0 = sg[idxb], e1 = sg[idxb + 64], e2 = sg[idxb + 128], e3 = sg[idxb + 192];
        if (idxb       < cnt) kproc(e0);
        if (idxb + 64  < cnt) kproc(e1);
        if (idxb + 128 < cnt) kproc(e2);
        if (idxb + 192 < cnt) kproc(e3);
    };

    kfilter(0, b0, 0, true);
    __syncthreads();
    kfilter(1, b1, 256, true);   kdense(0);
    __syncthreads();
    kfilter(0, b2, 512, true);   kdense(1);
    __syncthreads();
    kfilter(1, b3, 768, true);   kdense(0);
    __syncthreads();
    kfilter(0, b4, 1024, true);  kdense(1);
    __syncthreads();
    kfilter(1, b5, 1280, true);  kdense(0);
    __syncthreads();
    kfilter(0, b6, 1536, true);  kdense(1);
    __syncthreads();
    kfilter(1, b7, 1792, h7);    kdense(0);
    __syncthreads();
    kdense(1);

    for (int off = 32; off; off >>= 1) { u64 o = __shfl_down(pk, off); if (o > pk) pk = o; }
    if (lane == 0) wred[wid] = pk;
    __syncthreads();
    if (tid == 0) {
        for (int w = 1; w < 4; w++) if (wred[w] > pk) pk = wred[w];
        Wwin[blk] = pk;
    }
}

// ---------------- K5: per-row sort + exact cut + final race/merge ----------------
extern "C" __global__ void __launch_bounds__(1024)
k5_final(const float* __restrict__ smax, const int* __restrict__ sarg,
         const float* __restrict__ temps, const float* __restrict__ topps,
         const RowPar* __restrict__ par, const int* __restrict__ Wcnt,
         const u64* __restrict__ Wlist, const u64* __restrict__ Wwin,
         int* __restrict__ out) {
    int r = blockIdx.x, tid = threadIdx.x, lane = tid & 63, wid = tid >> 6;
    __shared__ u64 sb[CAP];
    __shared__ double wtot[16];
    __shared__ u64 wred[16];
    __shared__ int sh_js, sh_n, sh_gidx; __shared__ float sh_rm;
    RowPar p = par[r];
    if (tid == 0) {
        float rm = -3.402823466e38f; int gi = 0x7FFFFFFF;
        for (int j = 0; j < 16; j++) {
            float v = smax[r * 16 + j];
            if (v > rm) { rm = v; gi = sarg[r * 16 + j]; }
        }
        sh_rm = rm; sh_gidx = gi;
        int n = Wcnt[r]; if (n > CAP) n = CAP; sh_n = n;
        sh_js = 0x7FFFFFFF;
    }
    __syncthreads();
    int n = sh_n;
    int npad = 4; while (npad < n) npad <<= 1;
    const u64* lst = Wlist + (size_t)r * CAP;
    for (int i = tid; i < npad; i += 1024) sb[i] = (i < n) ? lst[i] : 0ULL;
    __syncthreads();
    for (int k = 2; k <= npad; k <<= 1) {
        for (int j = k >> 1; j > 0; j >>= 1) {
            for (int i = tid; i < npad; i += 1024) {
                int q2 = i ^ j;
                if (q2 > i) {
                    u64 a = sb[i], b = sb[q2];
                    bool desc = ((i & k) == 0);
                    if (desc ? (a < b) : (a > b)) { sb[i] = b; sb[q2] = a; }
                }
            }
            __syncthreads();
        }
    }
    int t2 = tid * 2;
    double f0 = 0.0, f1 = 0.0;
    if (t2 < npad) {
        f0 = (double)__uint_as_float((u32)(sb[t2] >> 32));
        f1 = (double)__uint_as_float((u32)(sb[t2 + 1] >> 32));
    }
    double c0 = f0, c1 = c0 + f1;
    double incl = c1;
    for (int off = 1; off < 64; off <<= 1) {
        double u = __shfl_up(incl, off);
        if (lane >= off) incl += u;
    }
    double excl = __shfl_up(incl, 1); if (lane == 0) excl = 0.0;
    double wt = __shfl(incl, 63);
    if (lane == 0) wtot[wid] = wt;
    __syncthreads();
    double cw = 0.0;
    for (int w = 0; w < wid; w++) cw += wtot[w];
    double cr = cw + excl;
    if (t2 < npad) {
        bool m0 = (p.M + (cr + c0)) > p.cutZ;
        bool m1 = (p.M + (cr + c1)) > p.cutZ;
        int cand = m0 ? t2 : m1 ? (t2 + 1) : 0x7FFFFFFF;
        if (cand != 0x7FFFFFFF) atomicMin(&sh_js, cand);
    }
    __syncthreads();
    float Traw = temps[r];
    if (tid == 0) {
        int js = sh_js; if (js > n) js = n;
        float T = fmaxf(Traw, 1e-5f), invT = 1.0f / T, xm = sh_rm * invT;
        int btop = (int)(__float_as_uint(q_of(sh_rm, invT, xm)) >> 18);
        if (js == 0 && p.bstar == btop) js = 1;   // mask[:,0]=False
        sh_js = js;
    }
    __syncthreads();
    int js = sh_js;
    u32 jbase = (u32)r * (u32)VV;
    u64 pk = 0ULL;
    for (int i = tid; i < js; i += 1024) {
        u64 key = sb[i];
        float qq = __uint_as_float((u32)(key >> 32));
        u32 v = ~(u32)key;
        float nz = noise_of(jbase + v);
        float sc = __fdividef(qq, nz);
        u64 e = ((u64)__float_as_uint(sc) << 32) | (u64)(~v);
        if (e > pk) pk = e;
    }
    if (tid < 16) { u64 w = Wwin[r * 16 + tid]; if (w > pk) pk = w; }
    for (int off = 32; off; off >>= 1) { u64 o = __shfl_down(pk, off); if (o > pk) pk = o; }
    if (lane == 0) wred[wid] = pk;
    __syncthreads();
    if (tid == 0) {
        for (int w = 1; w < 16; w++) if (wred[w] > pk) pk = wred[w];
        int bi = (int)(~(u32)pk);
        out[r] = (Traw <= 1e-10f) ? sh_gidx : bi;
    }
}

// ---------------- fallback: verified R2 monolithic kernel ----------------
extern "C" __global__ void __launch_bounds__(1024, 1)
sampler_fallback(const float* __restrict__ logits, const float* __restrict__ temps,
                 const float* __restrict__ topps, int* __restrict__ out)
{
    const int row = blockIdx.x;
    const int tid = threadIdx.x;
    const int lane = tid & 63;
    const int wid = tid >> 6;
    const float* L = logits + (size_t)row * VV;
    const float4* L4 = (const float4*)L;
    __shared__ __align__(16) unsigned char SMEM[32768];
    float* hist = (float*)SMEM;
    u64* sortbuf = (u64*)SMEM;
    __shared__ double wtot[16];
    __shared__ float wredf[16];
    __shared__ int wredi[16];
    __shared__ float sh_lmax;
    __shared__ int sh_gidx;
    __shared__ double sh_cutZ;
    __shared__ double sh_M;
    __shared__ int sh_bstar;
    __shared__ int sh_ng;
    __shared__ int sh_jstar;
    const float Traw = temps[row];
    const float T = fmaxf(Traw, 1e-5f);
    const float invT = 1.0f / T;
    const float tp = topps[row];
    float lmax = -3.402823466e38f; int lidx = 0x7FFFFFFF;
    for (int iv = tid; iv < NV4; iv += 1024) {
        float4 x = L4[iv];
        float m4 = fmaxf(fmaxf(x.x, x.y), fmaxf(x.z, x.w));
        if (m4 > lmax) {
            int base = iv * 4;
            if      (x.x == m4) lidx = base;
            else if (x.y == m4) lidx = base + 1;
            else if (x.z == m4) lidx = base + 2;
            else                lidx = base + 3;
            lmax = m4;
        }
    }
    for (int off = 32; off > 0; off >>= 1) {
        float ov = __shfl_down(lmax, off);
        int   oi = __shfl_down(lidx, off);
        if (ov > lmax || (ov == lmax && oi < lidx)) { lmax = ov; lidx = oi; }
    }
    if (lane == 0) { wredf[wid] = lmax; wredi[wid] = lidx; }
    for (int i = tid; i < NBUCK; i += 1024) hist[i] = 0.0f;
    __syncthreads();
    if (wid == 0) {
        float v = (lane < 16) ? wredf[lane] : -3.402823466e38f;
        int   i = (lane < 16) ? wredi[lane] : 0x7FFFFFFF;
        for (int off = 32; off > 0; off >>= 1) {
            float ov = __shfl_down(v, off);
            int   oi = __shfl_down(i, off);
            if (ov > v || (ov == v && oi < i)) { v = ov; i = oi; }
        }
        if (lane == 0) { sh_lmax = v; sh_gidx = i; }
    }
    __syncthreads();
    const float xm = sh_lmax * invT;
    const int gidx = sh_gidx;
    const int btop = (int)(__float_as_uint(q_of(sh_lmax, invT, xm)) >> 18);
    for (int iv = tid; iv < NV4; iv += 1024) {
        float4 x = L4[iv];
        float q0 = q_of(x.x, invT, xm), q1 = q_of(x.y, invT, xm);
        float q2 = q_of(x.z, invT, xm), q3 = q_of(x.w, invT, xm);
        u32 b0 = __float_as_uint(q0), b1 = __float_as_uint(q1);
        u32 b2 = __float_as_uint(q2), b3 = __float_as_uint(q3);
        if (b0) atomicAdd(&hist[b0 >> 18], q0);
        if (b1) atomicAdd(&hist[b1 >> 18], q1);
        if (b2) atomicAdd(&hist[b2 >> 18], q2);
        if (b3) atomicAdd(&hist[b3 >> 18], q3);
    }
    __syncthreads();
    float h0 = hist[4 * tid], h1 = hist[4 * tid + 1],
          h2 = hist[4 * tid + 2], h3 = hist[4 * tid + 3];
    double s3 = (double)h3, s2 = s3 + (double)h2, s1 = s2 + (double)h1, s0 = s1 + (double)h0;
    double incl = s0;
    for (int off = 1; off < 64; off <<= 1) {
        double u = __shfl_down(incl, off);
        if (lane + off < 64) incl += u;
    }
    double excl = __shfl_down(incl, 1);
    if (lane == 63) excl = 0.0;
    if (lane == 0) wtot[wid] = incl;
    __syncthreads();
    double cw = 0.0;
    for (int w = wid + 1; w < 16; w++) cw += wtot[w];
    const double carry = excl + cw;
    if (tid == 0) {
        sh_cutZ = (double)tp * (s0 + carry);
        sh_bstar = -1; sh_M = 0.0; sh_ng = 0; sh_jstar = 0x7FFFFFFF;
    }
    __syncthreads();
    const double cutZ = sh_cutZ;
    {
        double S0 = s0 + carry, S1 = s1 + carry, S2 = s2 + carry, S3 = s3 + carry;
        if (S0 > cutZ && S1 <= cutZ)    { sh_bstar = 4 * tid;     sh_M = S1; }
        if (S1 > cutZ && S2 <= cutZ)    { sh_bstar = 4 * tid + 1; sh_M = S2; }
        if (S2 > cutZ && S3 <= cutZ)    { sh_bstar = 4 * tid + 2; sh_M = S3; }
        if (S3 > cutZ && carry <= cutZ) { sh_bstar = 4 * tid + 3; sh_M = carry; }
    }
    __syncthreads();
    const int bstar = sh_bstar;
    const double M = sh_M;
    float bs = -1.0f; int bi = 0x7FFFFFFF;
    const u32 jbase = (u32)row * (u32)VV;
    for (int iv = tid; iv < NV4; iv += 1024) {
        float4 x = L4[iv];
        float qs[4] = {q_of(x.x, invT, xm), q_of(x.y, invT, xm),
                       q_of(x.z, invT, xm), q_of(x.w, invT, xm)};
        int base = iv * 4;
        #pragma unroll
        for (int k = 0; k < 4; k++) {
            u32 pb = __float_as_uint(qs[k]);
            if (pb == 0u) continue;
            int b = (int)(pb >> 18);
            if (b > bstar) {
                int v = base + k;
                float nz = noise_of(jbase + (u32)v);
                float sc = __fdividef(qs[k], nz);
                if (sc > bs || (sc == bs && v < bi)) { bs = sc; bi = v; }
            } else if (b == bstar) {
                int pos = atomicAdd(&sh_ng, 1);
                if (pos < 4096)
                    sortbuf[pos] = ((u64)pb << 32) | (u32)(~(u32)(base + k));
            }
        }
    }
    __syncthreads();
    if (bstar >= 0) {
        int n = sh_ng; if (n > 4096) n = 4096;
        int npad = 4; while (npad < n) npad <<= 1;
        for (int i = tid; i < npad; i += 1024) if (i >= n) sortbuf[i] = 0ULL;
        __syncthreads();
        for (int k = 2; k <= npad; k <<= 1) {
            for (int j = k >> 1; j > 0; j >>= 1) {
                for (int i = tid; i < npad; i += 1024) {
                    int pidx = i ^ j;
                    if (pidx > i) {
                        u64 a = sortbuf[i], b2 = sortbuf[pidx];
                        bool desc = ((i & k) == 0);
                        if (desc ? (a < b2) : (a > b2)) { sortbuf[i] = b2; sortbuf[pidx] = a; }
                    }
                }
                __syncthreads();
            }
        }
        double f0 = 0.0, f1 = 0.0, f2 = 0.0, f3 = 0.0;
        int t4 = tid * 4;
        if (t4 < npad) {
            f0 = (double)__uint_as_float((u32)(sortbuf[t4]     >> 32));
            f1 = (double)__uint_as_float((u32)(sortbuf[t4 + 1] >> 32));
            f2 = (double)__uint_as_float((u32)(sortbuf[t4 + 2] >> 32));
            f3 = (double)__uint_as_float((u32)(sortbuf[t4 + 3] >> 32));
        }
        double c0 = f0, c1 = c0 + f1, c2 = c1 + f2, c3 = c2 + f3;
        double incl2 = c3;
        for (int off = 1; off < 64; off <<= 1) {
            double u = __shfl_up(incl2, off);
            if (lane >= off) incl2 += u;
        }
        double excl2 = __shfl_up(incl2, 1);
        if (lane == 0) excl2 = 0.0;
        double wt = __shfl(incl2, 63);
        if (lane == 0) wtot[wid] = wt;
        __syncthreads();
        double cw2 = 0.0;
        for (int w = 0; w < wid; w++) cw2 += wtot[w];
        double cr = cw2 + excl2;
        if (t4 < npad) {
            bool m0 = (M + (cr + c0)) > cutZ;
            bool m1 = (M + (cr + c1)) > cutZ;
            bool m2 = (M + (cr + c2)) > cutZ;
            bool m3 = (M + (cr + c3)) > cutZ;
            int cand = m0 ? t4 : m1 ? (t4 + 1) : m2 ? (t4 + 2) : m3 ? (t4 + 3) : 0x7FFFFFFF;
            if (cand != 0x7FFFFFFF) atomicMin(&sh_jstar, cand);
        }
        __syncthreads();
        int jstar = sh_jstar; if (jstar > n) jstar = n;
        if (jstar == 0 && bstar == btop) jstar = 1;
        for (int i = tid; i < jstar; i += 1024) {
            u64 key = sortbuf[i];
            float qq = __uint_as_float((u32)(key >> 32));
            int v = (int)(~(u32)key);
            float nz = noise_of(jbase + (u32)v);
            float sc = __fdividef(qq, nz);
            if (sc > bs || (sc == bs && v < bi)) { bs = sc; bi = v; }
        }
    }
    for (int off = 32; off > 0; off >>= 1) {
        float ov = __shfl_down(bs, off);
        int   oi = __shfl_down(bi, off);
        if (ov > bs || (ov == bs && oi < bi)) { bs = ov; bi = oi; }
    }
    if (lane == 0) { wredf[wid] = bs; wredi[wid] = bi; }
    __syncthreads();
    if (tid == 0) {
        float v = wredf[0]; int i = wredi[0];
        for (int w = 1; w < 16; w++) {
            float ov = wredf[w]; int oi = wredi[w];
            if (ov > v || (ov == v && oi < i)) { v = ov; i = oi; }
        }
        out[row] = (Traw <= 1e-10f) ? gidx : i;
    }
}

extern "C" void kernel_launch(void* const* d_in, const int* in_sizes, int n_in,
                              void* d_out, int out_size, void* d_ws, size_t ws_size,
                              hipStream_t stream) {
    const float* logits = (const float*)d_in[0];
    const float* temps = (const float*)d_in[1];
    const float* topps = (const float*)d_in[2];
    int* out = (int*)d_out;
    (void)in_sizes; (void)n_in; (void)out_size;

    if (ws_size >= WS_TOTAL) {
        char* ws = (char*)d_ws;
        float* smax  = (float*)(ws + OFF_SMAX);
        int*   sarg  = (int*)(ws + OFF_SARG);
        u64*   wwin  = (u64*)(ws + OFF_WWIN);
        RowPar* par  = (RowPar*)(ws + OFF_PAR);
        int*   wcnt  = (int*)(ws + OFF_CNT);
        u64*   whist = (u64*)(ws + OFF_HIST);
        u64*   wlist = (u64*)(ws + OFF_LIST);
        k1_stats<<<BB * SLICES, 256, 0, stream>>>(logits, smax, sarg, whist, wcnt);
        k2_hist<<<BB * SLICES, 256, 0, stream>>>(logits, smax, temps, whist);
        k3_cut<<<BB, 1024, 0, stream>>>(whist, topps, par);
        k4_race<<<BB * SLICES, 256, 0, stream>>>(logits, smax, temps, par, wcnt, wlist, wwin);
        k5_final<<<BB, 1024, 0, stream>>>(smax, sarg, temps, topps, par, wcnt, wlist, wwin, out);
    } else {
        sampler_fallback<<<BB, 1024, 0, stream>>>(logits, temps, topps, out);
    }
}

// Round 6
// 348.167 us; speedup vs baseline: 1.2003x; 1.0000x over previous
//
#include <hip/hip_runtime.h>
#include <stdint.h>

typedef unsigned long long u64;
typedef uint32_t u32;

#define BB 256
#define VV 128000
#define NV4 (VV / 4)          // 32000 float4 per row
#define SLICES 16
#define SL4 (NV4 / SLICES)    // 2000 float4 per slice
#define NBUCK 4096
#define CAP 2048
#define QSCALE 1.099511627776e12f   // 2^40 fixed-point scale for q
#define QINV   (1.0 / 1099511627776.0)

// ---- workspace layout (bytes) ----
#define OFF_SMAX 0                          // float[256*16]
#define OFF_SARG (16*1024)                  // int[256*16]
#define OFF_WWIN (32*1024)                  // u64[256*16]
#define OFF_PAR  (64*1024)                  // RowPar[256]
#define OFF_CNT  (72*1024)                  // int[256]   (zeroed by k1)
#define OFF_HIST (80*1024)                  // u64[256*4096] (zeroed by k1)
#define OFF_LIST (OFF_HIST + (size_t)BB*NBUCK*8)  // u64[256*CAP]
#define WS_TOTAL (OFF_LIST + (size_t)BB*CAP*8)

struct RowPar { int bstar; float thr; double M; double cutZ; };

#if defined(__has_builtin)
# if __has_builtin(__builtin_amdgcn_sched_barrier)
#  define SCHED_FENCE() __builtin_amdgcn_sched_barrier(0)
# endif
#endif
#ifndef SCHED_FENCE
# define SCHED_FENCE() asm volatile("" ::: "memory")
#endif

__device__ __forceinline__ u32 rotl32(u32 v, u32 r) { return (v << r) | (v >> (32u - r)); }

// JAX partitionable threefry, key=(0,1), ctr=(0,j), bits=o0^o1.
// Verified bit-exact (R1-R5 absmax 0). DO NOT TOUCH.
__device__ __forceinline__ u32 threefry_bits(u32 j) {
    const u32 ks0 = 0u, ks1 = 1u, ks2 = 0x1BD11BDBu;
    u32 x0 = ks0, x1 = j + ks1;
    x0 += x1; x1 = rotl32(x1, 13); x1 ^= x0;
    x0 += x1; x1 = rotl32(x1, 15); x1 ^= x0;
    x0 += x1; x1 = rotl32(x1, 26); x1 ^= x0;
    x0 += x1; x1 = rotl32(x1, 6);  x1 ^= x0;
    x0 += ks1; x1 += ks2 + 1u;
    x0 += x1; x1 = rotl32(x1, 17); x1 ^= x0;
    x0 += x1; x1 = rotl32(x1, 29); x1 ^= x0;
    x0 += x1; x1 = rotl32(x1, 16); x1 ^= x0;
    x0 += x1; x1 = rotl32(x1, 24); x1 ^= x0;
    x0 += ks2; x1 += ks0 + 2u;
    x0 += x1; x1 = rotl32(x1, 13); x1 ^= x0;
    x0 += x1; x1 = rotl32(x1, 15); x1 ^= x0;
    x0 += x1; x1 = rotl32(x1, 26); x1 ^= x0;
    x0 += x1; x1 = rotl32(x1, 6);  x1 ^= x0;
    x0 += ks0; x1 += ks1 + 3u;
    x0 += x1; x1 = rotl32(x1, 17); x1 ^= x0;
    x0 += x1; x1 = rotl32(x1, 29); x1 ^= x0;
    x0 += x1; x1 = rotl32(x1, 16); x1 ^= x0;
    x0 += x1; x1 = rotl32(x1, 24); x1 ^= x0;
    x0 += ks1; x1 += ks2 + 4u;
    x0 += x1; x1 = rotl32(x1, 13); x1 ^= x0;
    x0 += x1; x1 = rotl32(x1, 15); x1 ^= x0;
    x0 += x1; x1 = rotl32(x1, 26); x1 ^= x0;
    x0 += x1; x1 = rotl32(x1, 6);  x1 ^= x0;
    x0 += ks2; x1 += ks0 + 5u;
    return x0 ^ x1;
}

__device__ __forceinline__ float q_of(float x, float invT, float xm) {
    return __expf(fmaf(x, invT, -xm));
}

__device__ __forceinline__ float noise_of(u32 j) {
    u32 bits = threefry_bits(j);
    float u = __uint_as_float((bits >> 9) | 0x3F800000u) - 1.0f;
    return fmaxf(-log1pf(-u), 1e-10f);
}

// Two-chain interleaved threefry: textual duplication of the verified chain
// with two independent register sets (a*, b*). Each chain's op sequence is
// byte-identical to threefry_bits -> bit-exact per chain; interleaving gives
// the compiler two independent dependency chains to hide VALU latency.
__device__ __forceinline__ void noise2_of(u32 ja, u32 jb, float& na, float& nb) {
    const u32 ks0 = 0u, ks1 = 1u, ks2 = 0x1BD11BDBu;
    u32 a0 = ks0, a1 = ja + ks1;
    u32 b0 = ks0, b1 = jb + ks1;
#define TF2_RND(r) a0 += a1; a1 = rotl32(a1, r); a1 ^= a0; \
                   b0 += b1; b1 = rotl32(b1, r); b1 ^= b0;
    TF2_RND(13) TF2_RND(15) TF2_RND(26) TF2_RND(6)
    a0 += ks1; a1 += ks2 + 1u;  b0 += ks1; b1 += ks2 + 1u;
    TF2_RND(17) TF2_RND(29) TF2_RND(16) TF2_RND(24)
    a0 += ks2; a1 += ks0 + 2u;  b0 += ks2; b1 += ks0 + 2u;
    TF2_RND(13) TF2_RND(15) TF2_RND(26) TF2_RND(6)
    a0 += ks0; a1 += ks1 + 3u;  b0 += ks0; b1 += ks1 + 3u;
    TF2_RND(17) TF2_RND(29) TF2_RND(16) TF2_RND(24)
    a0 += ks1; a1 += ks2 + 4u;  b0 += ks1; b1 += ks2 + 4u;
    TF2_RND(13) TF2_RND(15) TF2_RND(26) TF2_RND(6)
    a0 += ks2; a1 += ks0 + 5u;  b0 += ks2; b1 += ks0 + 5u;
#undef TF2_RND
    u32 xa = a0 ^ a1, xb = b0 ^ b1;
    float ua = __uint_as_float((xa >> 9) | 0x3F800000u) - 1.0f;
    float ub = __uint_as_float((xb >> 9) | 0x3F800000u) - 1.0f;
    na = fmaxf(-log1pf(-ua), 1e-10f);
    nb = fmaxf(-log1pf(-ub), 1e-10f);
}

// ---------------- K1: per-slice max/argmax + workspace zeroing ----------------
extern "C" __global__ void __launch_bounds__(256, 1)
k1_stats(const float* __restrict__ logits, float* __restrict__ smax,
         int* __restrict__ sarg, u64* __restrict__ Whist, int* __restrict__ Wcnt) {
    int blk = blockIdx.x, r = blk >> 4, s = blk & 15;
    int tid = threadIdx.x, lane = tid & 63, wid = tid >> 6;
    __shared__ float sf[4]; __shared__ int si[4];
    // zero this slice's chunk of the row hist + counter (replaces memsets)
    Whist[(size_t)r * NBUCK + s * 256 + tid] = 0ULL;
    if (s == 0 && tid == 0) Wcnt[r] = 0;
    const float4* L4 = (const float4*)(logits + (size_t)r * VV);
    int i0 = s * SL4 + tid;
    bool h7 = tid < (SL4 - 7 * 256);   // tid < 208
    float4 b0 = L4[i0],          b1 = L4[i0 + 256],  b2 = L4[i0 + 512];
    float4 b3 = L4[i0 + 768],    b4 = L4[i0 + 1024], b5 = L4[i0 + 1280];
    float4 b6 = L4[i0 + 1536],   b7 = L4[h7 ? i0 + 1792 : i0];
    SCHED_FENCE();                      // keep all 8 loads in flight (MLP=8)
    float m = -3.402823466e38f; int mi = 0x7FFFFFFF;
    auto upd = [&](float4 a, int iv) {
        float m4 = fmaxf(fmaxf(a.x, a.y), fmaxf(a.z, a.w));
        if (m4 > m) {                   // strict > keeps first occurrence
            int base = iv * 4;
            if      (a.x == m4) mi = base;
            else if (a.y == m4) mi = base + 1;
            else if (a.z == m4) mi = base + 2;
            else                mi = base + 3;
            m = m4;
        }
    };
    upd(b0, i0);        upd(b1, i0 + 256);  upd(b2, i0 + 512);  upd(b3, i0 + 768);
    upd(b4, i0 + 1024); upd(b5, i0 + 1280); upd(b6, i0 + 1536);
    if (h7) upd(b7, i0 + 1792);
    for (int off = 32; off; off >>= 1) {
        float ov = __shfl_down(m, off); int oi = __shfl_down(mi, off);
        if (ov > m || (ov == m && oi < mi)) { m = ov; mi = oi; }
    }
    if (lane == 0) { sf[wid] = m; si[wid] = mi; }
    __syncthreads();
    if (tid == 0) {
        for (int w = 1; w < 4; w++) {
            float ov = sf[w]; int oi = si[w];
            if (ov > m || (ov == m && oi < mi)) { m = ov; mi = oi; }
        }
        smax[blk] = m; sarg[blk] = mi;
    }
}

// -------- K2: u64 fixed-point LDS histogram (fast integer DS atomics) --------
extern "C" __global__ void __launch_bounds__(256, 1)
k2_hist(const float* __restrict__ logits, const float* __restrict__ smax,
        const float* __restrict__ temps, u64* __restrict__ Whist) {
    __shared__ u64 lh[NBUCK];           // 32 KB
    int blk = blockIdx.x, r = blk >> 4, s = blk & 15, tid = threadIdx.x;
    for (int i = tid; i < NBUCK; i += 256) lh[i] = 0ULL;
    float T = fmaxf(temps[r], 1e-5f), invT = 1.0f / T;
    float rm = -3.402823466e38f;
    for (int j = 0; j < 16; j++) rm = fmaxf(rm, smax[r * 16 + j]);
    float xm = rm * invT;
    __syncthreads();
    const float4* L4 = (const float4*)(logits + (size_t)r * VV);
    int i0 = s * SL4 + tid;
    bool h7 = tid < (SL4 - 7 * 256);
    float4 b0 = L4[i0],          b1 = L4[i0 + 256],  b2 = L4[i0 + 512];
    float4 b3 = L4[i0 + 768],    b4 = L4[i0 + 1024], b5 = L4[i0 + 1280];
    float4 b6 = L4[i0 + 1536],   b7 = L4[h7 ? i0 + 1792 : i0];
    SCHED_FENCE();
    auto proc = [&](float4 x) {
        float xs[4] = {x.x, x.y, x.z, x.w};
        #pragma unroll
        for (int k = 0; k < 4; k++) {
            float t = fmaf(xs[k], invT, -xm);
            // Bit-exact early-skip: for t < -27.7259 (= -40*ln2),
            // (u64)(q*QSCALE) == 0, so the atomicAdd was a no-op.
            if (t < -27.75f) continue;
            float q = __expf(t);
            u32 pb = __float_as_uint(q);
            if (pb) atomicAdd(&lh[pb >> 18], (u64)(q * QSCALE));
        }
    };
    proc(b0); proc(b1); proc(b2); proc(b3); proc(b4); proc(b5); proc(b6);
    if (h7) proc(b7);
    __syncthreads();
    u64* gh = Whist + (size_t)r * NBUCK;
    for (int i = tid; i < NBUCK; i += 256) {
        u64 v = lh[i];
        if (v) atomicAdd(&gh[i], v);
    }
}

// ---------------- K3: per-row suffix scan + cut + skip-threshold ----------------
extern "C" __global__ void __launch_bounds__(1024)
k3_cut(const u64* __restrict__ Whist, const float* __restrict__ topps,
       RowPar* __restrict__ par) {
    int r = blockIdx.x, tid = threadIdx.x, lane = tid & 63, wid = tid >> 6;
    __shared__ double wtot[16];
    __shared__ double sh_cutZ; __shared__ int sh_b; __shared__ double sh_M;
    const u64* gh = Whist + (size_t)r * NBUCK;
    double h0 = (double)gh[4 * tid]     * QINV;
    double h1 = (double)gh[4 * tid + 1] * QINV;
    double h2 = (double)gh[4 * tid + 2] * QINV;
    double h3 = (double)gh[4 * tid + 3] * QINV;
    double s3 = h3, s2 = s3 + h2, s1 = s2 + h1, s0 = s1 + h0;
    double incl = s0;
    for (int off = 1; off < 64; off <<= 1) {
        double u = __shfl_down(incl, off);
        if (lane + off < 64) incl += u;
    }
    double excl = __shfl_down(incl, 1); if (lane == 63) excl = 0.0;
    if (lane == 0) wtot[wid] = incl;
    if (tid == 0) { sh_b = -1; sh_M = 0.0; }
    __syncthreads();
    double cw = 0.0;
    for (int w = wid + 1; w < 16; w++) cw += wtot[w];
    double carry = excl + cw;
    if (tid == 0) sh_cutZ = (double)topps[r] * (s0 + carry);
    __syncthreads();
    double cutZ = sh_cutZ;
    double S0 = s0 + carry, S1 = s1 + carry, S2 = s2 + carry, S3 = s3 + carry;
    if (S0 > cutZ && S1 <= cutZ)    { sh_b = 4 * tid;     sh_M = S1; }
    if (S1 > cutZ && S2 <= cutZ)    { sh_b = 4 * tid + 1; sh_M = S2; }
    if (S2 > cutZ && S3 <= cutZ)    { sh_b = 4 * tid + 2; sh_M = S3; }
    if (S3 > cutZ && carry <= cutZ) { sh_b = 4 * tid + 3; sh_M = carry; }
    __syncthreads();
    if (tid == 0) {
        // conservative t-threshold: bucket(q_of(t)) >= bstar  =>  t >= thr
        float thr = -3.402823466e38f;
        if (sh_b > 0) {
            float qlo = __uint_as_float((u32)sh_b << 18);
            if (qlo >= 1.17549435e-38f) thr = logf(qlo) - 1e-3f;
        }
        RowPar p; p.bstar = sh_b; p.thr = thr; p.M = sh_M; p.cutZ = cutZ;
        par[r] = p;
    }
}

// -------- K4: R5 structure + bank-pad + paired-ILP threefry dense --------
// Same proven schedule (8 chunks, double-buffer, 9 barriers, register-prefix
// compaction). Changes vs R5, both targeting the measured stalls:
//  (1) segments padded to 257 u64 -> dense-read bases not bank-aligned
//      (kills the 4.1M-cycle 4-way conflict on seg[ph][dsg][idxb]).
//  (2) dense entries processed in PAIRS with noise2_of: two independent
//      threefry chains interleaved -> exposed dep-chain latency halved.
extern "C" __global__ void __launch_bounds__(256, 1)
k4_race(const float* __restrict__ logits, const float* __restrict__ smax,
        const float* __restrict__ temps, const RowPar* __restrict__ par,
        int* __restrict__ Wcnt, u64* __restrict__ Wlist, u64* __restrict__ Wwin) {
    int blk = blockIdx.x, r = blk >> 4, s = blk & 15;
    int tid = threadIdx.x, lane = tid & 63, wid = tid >> 6;
    __shared__ u64 seg[2][4][257];      // padded: stride 2056 B -> +2 banks/segment
    __shared__ int qn[2][4];
    __shared__ u64 wred[4];
    float T = fmaxf(temps[r], 1e-5f), invT = 1.0f / T;
    float rm = -3.402823466e38f;
    for (int j = 0; j < 16; j++) rm = fmaxf(rm, smax[r * 16 + j]);
    float xm = rm * invT;
    int bstar = par[r].bstar;
    float thr = par[r].thr;
    const float4* L4 = (const float4*)(logits + (size_t)r * VV);
    u32 jbase = (u32)r * (u32)VV;
    u64 pk = 0ULL;
    const u64 lanelt = (1ULL << lane) - 1ULL;
    const int dsg = tid & 3, idxb = tid >> 2;   // dense-sweep coords
    int i0 = s * SL4 + tid;
    bool h7 = tid < (SL4 - 7 * 256);
    float4 b0 = L4[i0],          b1 = L4[i0 + 256],  b2 = L4[i0 + 512];
    float4 b3 = L4[i0 + 768],    b4 = L4[i0 + 1024], b5 = L4[i0 + 1280];
    float4 b6 = L4[i0 + 1536],   b7 = L4[h7 ? i0 + 1792 : i0];
    SCHED_FENCE();                      // keep all 8 loads in flight (MLP=8)

    auto kfilter = [&](int ph, float4 v, int off, bool valid) {
        float t0 = fmaf(v.x, invT, -xm), t1 = fmaf(v.y, invT, -xm);
        float t2 = fmaf(v.z, invT, -xm), t3 = fmaf(v.w, invT, -xm);
        int base = (i0 + off) * 4;
        bool p0 = valid && (t0 >= thr), p1 = valid && (t1 >= thr);
        bool p2 = valid && (t2 >= thr), p3 = valid && (t3 >= thr);
        u64 m0 = __ballot(p0), m1 = __ballot(p1);
        u64 m2 = __ballot(p2), m3 = __ballot(p3);
        int c0 = __popcll(m0), c01 = c0 + __popcll(m1), c012 = c01 + __popcll(m2);
        u64* sg = seg[ph][wid];
        if (p0) sg[       __popcll(m0 & lanelt)] = ((u64)__float_as_uint(t0) << 32) | (u32)(base + 0);
        if (p1) sg[c0   + __popcll(m1 & lanelt)] = ((u64)__float_as_uint(t1) << 32) | (u32)(base + 1);
        if (p2) sg[c01  + __popcll(m2 & lanelt)] = ((u64)__float_as_uint(t2) << 32) | (u32)(base + 2);
        if (p3) sg[c012 + __popcll(m3 & lanelt)] = ((u64)__float_as_uint(t3) << 32) | (u32)(base + 3);
        if (lane == 0) qn[ph][wid] = c012 + __popcll(m3);
    };

    // paired dense processing: both expf's up front; one interleaved 2-chain
    // threefry covers both entries' noise. Per-chain arithmetic identical to
    // the scalar path -> bit-exact.
    auto kproc2 = [&](u64 ea, u64 eb, bool va, bool vb) {
        float ta = __uint_as_float((u32)(ea >> 32));
        float tb = __uint_as_float((u32)(eb >> 32));
        u32 dva = (u32)ea, dvb = (u32)eb;
        float qa = __expf(ta), qb = __expf(tb);
        u32 pba = __float_as_uint(qa), pbb = __float_as_uint(qb);
        int bba = (int)(pba >> 18), bbb = (int)(pbb >> 18);
        bool ra = va && pba && (bba > bstar);
        bool rb = vb && pbb && (bbb > bstar);
        if (ra || rb) {
            float nza, nzb;
            noise2_of(jbase + dva, jbase + dvb, nza, nzb);
            if (ra) {
                float sc = __fdividef(qa, nza);
                u64 ee = ((u64)__float_as_uint(sc) << 32) | (u64)(~dva);
                if (ee > pk) pk = ee;
            }
            if (rb) {
                float sc = __fdividef(qb, nzb);
                u64 ee = ((u64)__float_as_uint(sc) << 32) | (u64)(~dvb);
                if (ee > pk) pk = ee;
            }
        }
        if (va && pba && bba == bstar) {
            int pos = atomicAdd(&Wcnt[r], 1);
            if (pos < CAP)
                Wlist[(size_t)r * CAP + pos] = ((u64)pba << 32) | (u64)(~dva);
        }
        if (vb && pbb && bbb == bstar) {
            int pos = atomicAdd(&Wcnt[r], 1);
            if (pos < CAP)
                Wlist[(size_t)r * CAP + pos] = ((u64)pbb << 32) | (u64)(~dvb);
        }
    };
    auto kdense = [&](int ph) {
        int cnt = qn[ph][dsg];
        const u64* sg = seg[ph][dsg];
        u64 e0 = sg[idxb], e1 = sg[idxb + 64], e2 = sg[idxb + 128], e3 = sg[idxb + 192];
        bool v0 = idxb < cnt, v1 = idxb + 64 < cnt;
        bool v2 = idxb + 128 < cnt, v3 = idxb + 192 < cnt;
        if (v0 | v1) kproc2(e0, e1, v0, v1);
        if (v2 | v3) kproc2(e2, e3, v2, v3);
    };

    kfilter(0, b0, 0, true);
    __syncthreads();
    kfilter(1, b1, 256, true);   kdense(0);
    __syncthreads();
    kfilter(0, b2, 512, true);   kdense(1);
    __syncthreads();
    kfilter(1, b3, 768, true);   kdense(0);
    __syncthreads();
    kfilter(0, b4, 1024, true);  kdense(1);
    __syncthreads();
    kfilter(1, b5, 1280, true);  kdense(0);
    __syncthreads();
    kfilter(0, b6, 1536, true);  kdense(1);
    __syncthreads();
    kfilter(1, b7, 1792, h7);    kdense(0);
    __syncthreads();
    kdense(1);

    for (int off = 32; off; off >>= 1) { u64 o = __shfl_down(pk, off); if (o > pk) pk = o; }
    if (lane == 0) wred[wid] = pk;
    __syncthreads();
    if (tid == 0) {
        for (int w = 1; w < 4; w++) if (wred[w] > pk) pk = wred[w];
        Wwin[blk] = pk;
    }
}

// ---------------- K5: per-row sort + exact cut + final race/merge ----------------
extern "C" __global__ void __launch_bounds__(1024)
k5_final(const float* __restrict__ smax, const int* __restrict__ sarg,
         const float* __restrict__ temps, const float* __restrict__ topps,
         const RowPar* __restrict__ par, const int* __restrict__ Wcnt,
         const u64* __restrict__ Wlist, const u64* __restrict__ Wwin,
         int* __restrict__ out) {
    int r = blockIdx.x, tid = threadIdx.x, lane = tid & 63, wid = tid >> 6;
    __shared__ u64 sb[CAP];
    __shared__ double wtot[16];
    __shared__ u64 wred[16];
    __shared__ int sh_js, sh_n, sh_gidx; __shared__ float sh_rm;
    RowPar p = par[r];
    if (tid == 0) {
        float rm = -3.402823466e38f; int gi = 0x7FFFFFFF;
        for (int j = 0; j < 16; j++) {
            float v = smax[r * 16 + j];
            if (v > rm) { rm = v; gi = sarg[r * 16 + j]; }
        }
        sh_rm = rm; sh_gidx = gi;
        int n = Wcnt[r]; if (n > CAP) n = CAP; sh_n = n;
        sh_js = 0x7FFFFFFF;
    }
    __syncthreads();
    int n = sh_n;
    int npad = 4; while (npad < n) npad <<= 1;
    const u64* lst = Wlist + (size_t)r * CAP;
    for (int i = tid; i < npad; i += 1024) sb[i] = (i < n) ? lst[i] : 0ULL;
    __syncthreads();
    for (int k = 2; k <= npad; k <<= 1) {
        for (int j = k >> 1; j > 0; j >>= 1) {
            for (int i = tid; i < npad; i += 1024) {
                int q2 = i ^ j;
                if (q2 > i) {
                    u64 a = sb[i], b = sb[q2];
                    bool desc = ((i & k) == 0);
                    if (desc ? (a < b) : (a > b)) { sb[i] = b; sb[q2] = a; }
                }
            }
            __syncthreads();
        }
    }
    int t2 = tid * 2;
    double f0 = 0.0, f1 = 0.0;
    if (t2 < npad) {
        f0 = (double)__uint_as_float((u32)(sb[t2] >> 32));
        f1 = (double)__uint_as_float((u32)(sb[t2 + 1] >> 32));
    }
    double c0 = f0, c1 = c0 + f1;
    double incl = c1;
    for (int off = 1; off < 64; off <<= 1) {
        double u = __shfl_up(incl, off);
        if (lane >= off) incl += u;
    }
    double excl = __shfl_up(incl, 1); if (lane == 0) excl = 0.0;
    double wt = __shfl(incl, 63);
    if (lane == 0) wtot[wid] = wt;
    __syncthreads();
    double cw = 0.0;
    for (int w = 0; w < wid; w++) cw += wtot[w];
    double cr = cw + excl;
    if (t2 < npad) {
        bool m0 = (p.M + (cr + c0)) > p.cutZ;
        bool m1 = (p.M + (cr + c1)) > p.cutZ;
        int cand = m0 ? t2 : m1 ? (t2 + 1) : 0x7FFFFFFF;
        if (cand != 0x7FFFFFFF) atomicMin(&sh_js, cand);
    }
    __syncthreads();
    float Traw = temps[r];
    if (tid == 0) {
        int js = sh_js; if (js > n) js = n;
        float T = fmaxf(Traw, 1e-5f), invT = 1.0f / T, xm = sh_rm * invT;
        int btop = (int)(__float_as_uint(q_of(sh_rm, invT, xm)) >> 18);
        if (js == 0 && p.bstar == btop) js = 1;   // mask[:,0]=False
        sh_js = js;
    }
    __syncthreads();
    int js = sh_js;
    u32 jbase = (u32)r * (u32)VV;
    u64 pk = 0ULL;
    for (int i = tid; i < js; i += 1024) {
        u64 key = sb[i];
        float qq = __uint_as_float((u32)(key >> 32));
        u32 v = ~(u32)key;
        float nz = noise_of(jbase + v);
        float sc = __fdividef(qq, nz);
        u64 e = ((u64)__float_as_uint(sc) << 32) | (u64)(~v);
        if (e > pk) pk = e;
    }
    if (tid < 16) { u64 w = Wwin[r * 16 + tid]; if (w > pk) pk = w; }
    for (int off = 32; off; off >>= 1) { u64 o = __shfl_down(pk, off); if (o > pk) pk = o; }
    if (lane == 0) wred[wid] = pk;
    __syncthreads();
    if (tid == 0) {
        for (int w = 1; w < 16; w++) if (wred[w] > pk) pk = wred[w];
        int bi = (int)(~(u32)pk);
        out[r] = (Traw <= 1e-10f) ? sh_gidx : bi;
    }
}

// ---------------- fallback: verified R2 monolithic kernel ----------------
extern "C" __global__ void __launch_bounds__(1024, 1)
sampler_fallback(const float* __restrict__ logits, const float* __restrict__ temps,
                 const float* __restrict__ topps, int* __restrict__ out)
{
    const int row = blockIdx.x;
    const int tid = threadIdx.x;
    const int lane = tid & 63;
    const int wid = tid >> 6;
    const float* L = logits + (size_t)row * VV;
    const float4* L4 = (const float4*)L;
    __shared__ __align__(16) unsigned char SMEM[32768];
    float* hist = (float*)SMEM;
    u64* sortbuf = (u64*)SMEM;
    __shared__ double wtot[16];
    __shared__ float wredf[16];
    __shared__ int wredi[16];
    __shared__ float sh_lmax;
    __shared__ int sh_gidx;
    __shared__ double sh_cutZ;
    __shared__ double sh_M;
    __shared__ int sh_bstar;
    __shared__ int sh_ng;
    __shared__ int sh_jstar;
    const float Traw = temps[row];
    const float T = fmaxf(Traw, 1e-5f);
    const float invT = 1.0f / T;
    const float tp = topps[row];
    float lmax = -3.402823466e38f; int lidx = 0x7FFFFFFF;
    for (int iv = tid; iv < NV4; iv += 1024) {
        float4 x = L4[iv];
        float m4 = fmaxf(fmaxf(x.x, x.y), fmaxf(x.z, x.w));
        if (m4 > lmax) {
            int base = iv * 4;
            if      (x.x == m4) lidx = base;
            else if (x.y == m4) lidx = base + 1;
            else if (x.z == m4) lidx = base + 2;
            else                lidx = base + 3;
            lmax = m4;
        }
    }
    for (int off = 32; off > 0; off >>= 1) {
        float ov = __shfl_down(lmax, off);
        int   oi = __shfl_down(lidx, off);
        if (ov > lmax || (ov == lmax && oi < lidx)) { lmax = ov; lidx = oi; }
    }
    if (lane == 0) { wredf[wid] = lmax; wredi[wid] = lidx; }
    for (int i = tid; i < NBUCK; i += 1024) hist[i] = 0.0f;
    __syncthreads();
    if (wid == 0) {
        float v = (lane < 16) ? wredf[lane] : -3.402823466e38f;
        int   i = (lane < 16) ? wredi[lane] : 0x7FFFFFFF;
        for (int off = 32; off > 0; off >>= 1) {
            float ov = __shfl_down(v, off);
            int   oi = __shfl_down(i, off);
            if (ov > v || (ov == v && oi < i)) { v = ov; i = oi; }
        }
        if (lane == 0) { sh_lmax = v; sh_gidx = i; }
    }
    __syncthreads();
    const float xm = sh_lmax * invT;
    const int gidx = sh_gidx;
    const int btop = (int)(__float_as_uint(q_of(sh_lmax, invT, xm)) >> 18);
    for (int iv = tid; iv < NV4; iv += 1024) {
        float4 x = L4[iv];
        float q0 = q_of(x.x, invT, xm), q1 = q_of(x.y, invT, xm);
        float q2 = q_of(x.z, invT, xm), q3 = q_of(x.w, invT, xm);
        u32 b0 = __float_as_uint(q0), b1 = __float_as_uint(q1);
        u32 b2 = __float_as_uint(q2), b3 = __float_as_uint(q3);
        if (b0) atomicAdd(&hist[b0 >> 18], q0);
        if (b1) atomicAdd(&hist[b1 >> 18], q1);
        if (b2) atomicAdd(&hist[b2 >> 18], q2);
        if (b3) atomicAdd(&hist[b3 >> 18], q3);
    }
    __syncthreads();
    float h0 = hist[4 * tid], h1 = hist[4 * tid + 1],
          h2 = hist[4 * tid + 2], h3 = hist[4 * tid + 3];
    double s3 = (double)h3, s2 = s3 + (double)h2, s1 = s2 + (double)h1, s0 = s1 + (double)h0;
    double incl = s0;
    for (int off = 1; off < 64; off <<= 1) {
        double u = __shfl_down(incl, off);
        if (lane + off < 64) incl += u;
    }
    double excl = __shfl_down(incl, 1);
    if (lane == 63) excl = 0.0;
    if (lane == 0) wtot[wid] = incl;
    __syncthreads();
    double cw = 0.0;
    for (int w = wid + 1; w < 16; w++) cw += wtot[w];
    const double carry = excl + cw;
    if (tid == 0) {
        sh_cutZ = (double)tp * (s0 + carry);
        sh_bstar = -1; sh_M = 0.0; sh_ng = 0; sh_jstar = 0x7FFFFFFF;
    }
    __syncthreads();
    const double cutZ = sh_cutZ;
    {
        double S0 = s0 + carry, S1 = s1 + carry, S2 = s2 + carry, S3 = s3 + carry;
        if (S0 > cutZ && S1 <= cutZ)    { sh_bstar = 4 * tid;     sh_M = S1; }
        if (S1 > cutZ && S2 <= cutZ)    { sh_bstar = 4 * tid + 1; sh_M = S2; }
        if (S2 > cutZ && S3 <= cutZ)    { sh_bstar = 4 * tid + 2; sh_M = S3; }
        if (S3 > cutZ && carry <= cutZ) { sh_bstar = 4 * tid + 3; sh_M = carry; }
    }
    __syncthreads();
    const int bstar = sh_bstar;
    const double M = sh_M;
    float bs = -1.0f; int bi = 0x7FFFFFFF;
    const u32 jbase = (u32)row * (u32)VV;
    for (int iv = tid; iv < NV4; iv += 1024) {
        float4 x = L4[iv];
        float qs[4] = {q_of(x.x, invT, xm), q_of(x.y, invT, xm),
                       q_of(x.z, invT, xm), q_of(x.w, invT, xm)};
        int base = iv * 4;
        #pragma unroll
        for (int k = 0; k < 4; k++) {
            u32 pb = __float_as_uint(qs[k]);
            if (pb == 0u) continue;
            int b = (int)(pb >> 18);
            if (b > bstar) {
                int v = base + k;
                float nz = noise_of(jbase + (u32)v);
                float sc = __fdividef(qs[k], nz);
                if (sc > bs || (sc == bs && v < bi)) { bs = sc; bi = v; }
            } else if (b == bstar) {
                int pos = atomicAdd(&sh_ng, 1);
                if (pos < 4096)
                    sortbuf[pos] = ((u64)pb << 32) | (u32)(~(u32)(base + k));
            }
        }
    }
    __syncthreads();
    if (bstar >= 0) {
        int n = sh_ng; if (n > 4096) n = 4096;
        int npad = 4; while (npad < n) npad <<= 1;
        for (int i = tid; i < npad; i += 1024) if (i >= n) sortbuf[i] = 0ULL;
        __syncthreads();
        for (int k = 2; k <= npad; k <<= 1) {
            for (int j = k >> 1; j > 0; j >>= 1) {
                for (int i = tid; i < npad; i += 1024) {
                    int pidx = i ^ j;
                    if (pidx > i) {
                        u64 a = sortbuf[i], b2 = sortbuf[pidx];
                        bool desc = ((i & k) == 0);
                        if (desc ? (a < b2) : (a > b2)) { sortbuf[i] = b2; sortbuf[pidx] = a; }
                    }
                }
                __syncthreads();
            }
        }
        double f0 = 0.0, f1 = 0.0, f2 = 0.0, f3 = 0.0;
        int t4 = tid * 4;
        if (t4 < npad) {
            f0 = (double)__uint_as_float((u32)(sortbuf[t4]     >> 32));
            f1 = (double)__uint_as_float((u32)(sortbuf[t4 + 1] >> 32));
            f2 = (double)__uint_as_float((u32)(sortbuf[t4 + 2] >> 32));
            f3 = (double)__uint_as_float((u32)(sortbuf[t4 + 3] >> 32));
        }
        double c0 = f0, c1 = c0 + f1, c2 = c1 + f2, c3 = c2 + f3;
        double incl2 = c3;
        for (int off = 1; off < 64; off <<= 1) {
            double u = __shfl_up(incl2, off);
            if (lane >= off) incl2 += u;
        }
        double excl2 = __shfl_up(incl2, 1);
        if (lane == 0) excl2 = 0.0;
        double wt = __shfl(incl2, 63);
        if (lane == 0) wtot[wid] = wt;
        __syncthreads();
        double cw2 = 0.0;
        for (int w = 0; w < wid; w++) cw2 += wtot[w];
        double cr = cw2 + excl2;
        if (t4 < npad) {
            bool m0 = (M + (cr + c0)) > cutZ;
            bool m1 = (M + (cr + c1)) > cutZ;
            bool m2 = (M + (cr + c2)) > cutZ;
            bool m3 = (M + (cr + c3)) > cutZ;
            int cand = m0 ? t4 : m1 ? (t4 + 1) : m2 ? (t4 + 2) : m3 ? (t4 + 3) : 0x7FFFFFFF;
            if (cand != 0x7FFFFFFF) atomicMin(&sh_jstar, cand);
        }
        __syncthreads();
        int jstar = sh_jstar; if (jstar > n) jstar = n;
        if (jstar == 0 && bstar == btop) jstar = 1;
        for (int i = tid; i < jstar; i += 1024) {
            u64 key = sortbuf[i];
            float qq = __uint_as_float((u32)(key >> 32));
            int v = (int)(~(u32)key);
            float nz = noise_of(jbase + (u32)v);
            float sc = __fdividef(qq, nz);
            if (sc > bs || (sc == bs && v < bi)) { bs = sc; bi = v; }
        }
    }
    for (int off = 32; off > 0; off >>= 1) {
        float ov = __shfl_down(bs, off);
        int   oi = __shfl_down(bi, off);
        if (ov > bs || (ov == bs && oi < bi)) { bs = ov; bi = oi; }
    }
    if (lane == 0) { wredf[wid] = bs; wredi[wid] = bi; }
    __syncthreads();
    if (tid == 0) {
        float v = wredf[0]; int i = wredi[0];
        for (int w = 1; w < 16; w++) {
            float ov = wredf[w]; int oi = wredi[w];
            if (ov > v || (ov == v && oi < i)) { v = ov; i = oi; }
        }
        out[row] = (Traw <= 1e-10f) ? gidx : i;
    }
}

extern "C" void kernel_launch(void* const* d_in, const int* in_sizes, int n_in,
                              void* d_out, int out_size, void* d_ws, size_t ws_size,
                              hipStream_t stream) {
    const float* logits = (const float*)d_in[0];
    const float* temps = (const float*)d_in[1];
    const float* topps = (const float*)d_in[2];
    int* out = (int*)d_out;
    (void)in_sizes; (void)n_in; (void)out_size;

    if (ws_size >= WS_TOTAL) {
        char* ws = (char*)d_ws;
        float* smax  = (float*)(ws + OFF_SMAX);
        int*   sarg  = (int*)(ws + OFF_SARG);
        u64*   wwin  = (u64*)(ws + OFF_WWIN);
        RowPar* par  = (RowPar*)(ws + OFF_PAR);
        int*   wcnt  = (int*)(ws + OFF_CNT);
        u64*   whist = (u64*)(ws + OFF_HIST);
        u64*   wlist = (u64*)(ws + OFF_LIST);
        k1_stats<<<BB * SLICES, 256, 0, stream>>>(logits, smax, sarg, whist, wcnt);
        k2_hist<<<BB * SLICES, 256, 0, stream>>>(logits, smax, temps, whist);
        k3_cut<<<BB, 1024, 0, stream>>>(whist, topps, par);
        k4_race<<<BB * SLICES, 256, 0, stream>>>(logits, smax, temps, par, wcnt, wlist, wwin);
        k5_final<<<BB, 1024, 0, stream>>>(smax, sarg, temps, topps, par, wcnt, wlist, wwin, out);
    } else {
        sampler_fallback<<<BB, 1024, 0, stream>>>(logits, temps, topps, out);
    }
}